// Round 4
// baseline (554.883 us; speedup 1.0000x reference)
//
#include <hip/hip_runtime.h>

// RBM CD-1 step on MI355X — round 12.
// = round-11 kernel (verified 528.6us; r9-equivalent) + ONE delta:
// XCD-chunked bijective blockIdx swizzle [T1] on every gemm256 launch.
// All launches have nwg == 256 (divisible by 8) -> chunked remap is
// bijective. Each XCD now owns a contiguous 32-block chunk (one full
// N-panel for G1/G2/G4/G5, one K-slice for G3/G6): B-panels 32-way shared
// in one L2 instead of 4-way across 8 L2s; uni prefetch lines face less
// eviction pressure. Pure index permutation — no sync/structure change.

typedef unsigned short u16;
typedef short s16x8 __attribute__((ext_vector_type(8)));
typedef float f32x4 __attribute__((ext_vector_type(4)));
typedef u16 u16x4 __attribute__((ext_vector_type(4)));
typedef u16 u16x8 __attribute__((ext_vector_type(8)));

constexpr int Bn = 8192, Vn = 2048, Hn = 1024;
constexpr size_t VH = (size_t)Vn * Hn;
constexpr size_t BH = (size_t)Bn * Hn;
constexpr size_t OUT_RECON = BH;                        // 8388608
constexpr size_t OUT_WGRAD = OUT_RECON + 1;             // 8388609
constexpr size_t OUT_VBG   = OUT_WGRAD + VH;            // 10485761
constexpr size_t OUT_HBG   = OUT_VBG + Vn;              // 10487809

__device__ __forceinline__ u16 f2bf(float x) {
  union { float f; unsigned u; } a; a.f = x;
  unsigned r = a.u + 0x7FFFu + ((a.u >> 16) & 1u);   // RNE
  return (u16)(r >> 16);
}
__device__ __forceinline__ float bf2f(u16 h) {
  union { unsigned u; float f; } a; a.u = ((unsigned)h) << 16;
  return a.f;
}
__device__ __forceinline__ float sigmoidf_(float x) {
  return 1.0f / (1.0f + __expf(-x));
}

using gptr_t = const unsigned int __attribute__((address_space(1)))*;
using lptr_t = unsigned int __attribute__((address_space(3)))*;

__device__ __forceinline__ void gload16(const u16* g, u16* l) {
  __builtin_amdgcn_global_load_lds((gptr_t)(unsigned long long)g,
                                   (lptr_t)(unsigned long long)l, 16, 0, 0);
}

// ---------------- prep kernels ----------------

// v[B,V] f32 -> v_cat[B,2V]=[hi|lo], vT[V,B] (hi, transposed), vbd partials.
__global__ void prep_vt_k(const float* __restrict__ v, u16* __restrict__ vcat,
                          u16* __restrict__ vT, float* __restrict__ vbd_p) {
  __shared__ u16 tile[64][68];
  __shared__ float cs[16][64];
  const int b0 = blockIdx.x * 64, c0 = blockIdx.y * 64;
  const int t = threadIdx.x;
  const int rg = t >> 4;          // 0..15 row group
  const int cg = (t & 15) << 2;   // col *4
  float ca[4] = {0.f, 0.f, 0.f, 0.f};
#pragma unroll
  for (int i = 0; i < 4; ++i) {
    int r = rg + 16 * i;
    f32x4 x = *(const f32x4*)&v[(size_t)(b0 + r) * Vn + c0 + cg];
    u16x4 hi, lo;
#pragma unroll
    for (int j = 0; j < 4; ++j) {
      hi[j] = f2bf(x[j]);
      lo[j] = f2bf(x[j] - bf2f(hi[j]));
      tile[r][cg + j] = hi[j];
      ca[j] += x[j];
    }
    *(u16x4*)&vcat[(size_t)(b0 + r) * (2 * Vn) + c0 + cg] = hi;
    *(u16x4*)&vcat[(size_t)(b0 + r) * (2 * Vn) + Vn + c0 + cg] = lo;
  }
#pragma unroll
  for (int j = 0; j < 4; ++j) cs[rg][cg + j] = ca[j];
  __syncthreads();
  if (t < 64) {
    float s = 0.f;
#pragma unroll
    for (int k = 0; k < 16; ++k) s += cs[k][t];
    vbd_p[(size_t)blockIdx.x * Vn + c0 + t] = s;   // [128][2048]
  }
#pragma unroll
  for (int s2 = 0; s2 < 2; ++s2) {
    int c = t >> 2;
    int seg = (t & 3) + 4 * s2;
    u16x8 pk;
#pragma unroll
    for (int i = 0; i < 8; ++i) pk[i] = tile[seg * 8 + i][c];
    *(u16x8*)&vT[(size_t)(c0 + c) * Bn + b0 + seg * 8] = pk;
  }
}

// w[V,H] f32 -> w_cat[V,2H]=[hi|lo] and wT_cat[H,2V]=[hi|lo] (transposed)
__global__ void prep_w_k(const float* __restrict__ w, u16* __restrict__ w_cat,
                         u16* __restrict__ wTc) {
  __shared__ float tile[64][65];
  int v0 = blockIdx.x * 64, h0 = blockIdx.y * 64;
  int t = threadIdx.x, c = t & 63, r = t >> 6;
  for (int rr = r; rr < 64; rr += 4) {
    float x = w[(size_t)(v0 + rr) * Hn + h0 + c];
    tile[rr][c] = x;
    u16 hi = f2bf(x), lo = f2bf(x - bf2f(hi));
    w_cat[(size_t)(v0 + rr) * (2 * Hn) + h0 + c]      = hi;
    w_cat[(size_t)(v0 + rr) * (2 * Hn) + Hn + h0 + c] = lo;
  }
  __syncthreads();
  for (int rr = r; rr < 64; rr += 4) {
    float x = tile[c][rr];  // = w[v0+c][h0+rr]
    u16 hi = f2bf(x), lo = f2bf(x - bf2f(hi));
    size_t ro = (size_t)(h0 + rr) * (2 * Vn);
    wTc[ro + v0 + c]      = hi;
    wTc[ro + Vn + v0 + c] = lo;
  }
}

// ---- sampling epilogue for split-K [B,H] pre-activations ----------------
template <int M>
__global__ void epi_h_k(const float* __restrict__ p0, const float* __restrict__ p1,
                        const float* __restrict__ bias, const float* __restrict__ uni,
                        float* __restrict__ f32out, u16* __restrict__ hp_out,
                        u16* __restrict__ hbin_out, u16* __restrict__ tout,
                        float* __restrict__ colp) {
  __shared__ u16 tile[64][68];
  __shared__ float cs[16][64];
  const int b0 = blockIdx.x * 64, c0 = blockIdx.y * 64;
  const int t = threadIdx.x;
  const int rg = t >> 4, cg = (t & 15) << 2;
  float ca[4] = {0.f, 0.f, 0.f, 0.f};
#pragma unroll
  for (int i = 0; i < 4; ++i) {
    int r = rg + 16 * i;
    size_t e = (size_t)(b0 + r) * Hn + c0 + cg;
    f32x4 a = *(const f32x4*)&p0[e];
    f32x4 b = *(const f32x4*)&p1[e];
    f32x4 uu = *(const f32x4*)&uni[e];
    f32x4 hpv;
    u16x4 hb16, qv;
#pragma unroll
    for (int j = 0; j < 4; ++j) {
      float hp = sigmoidf_(a[j] + b[j] + bias[c0 + cg + j]);
      u16 qb = (hp > uu[j]) ? (u16)0x3F80 : (u16)0;
      tile[r][cg + j] = qb;
      if constexpr (M == 1) {
        hpv[j] = hp; hb16[j] = f2bf(hp); qv[j] = qb;
        ca[j] += hp;
      } else {
        ca[j] += (qb ? 1.f : 0.f);
      }
    }
    if constexpr (M == 1) {
      *(f32x4*)&f32out[e] = hpv;        // h_prediction (overwrites p0 region)
      *(u16x4*)&hp_out[e] = hb16;
      *(u16x4*)&hbin_out[e] = qv;
    }
  }
#pragma unroll
  for (int j = 0; j < 4; ++j) cs[rg][cg + j] = ca[j];
  __syncthreads();
  if (t < 64) {
    float s = 0.f;
#pragma unroll
    for (int k = 0; k < 16; ++k) s += cs[k][t];
    colp[(size_t)blockIdx.x * Hn + c0 + t] = s;   // [128][1024]
  }
#pragma unroll
  for (int s2 = 0; s2 < 2; ++s2) {
    int c = t >> 2;
    int seg = (t & 3) + 4 * s2;
    u16x8 pk;
#pragma unroll
    for (int i = 0; i < 8; ++i) pk[i] = tile[seg * 8 + i][c];
    *(u16x8*)&tout[(size_t)(c0 + c) * Bn + b0 + seg * 8] = pk;
  }
}

// ---------------- GEMM 256x256, BK=32, 8 waves, depth-4 counted pipeline --
// MODE 1: G1 split-K x2 partial (A remap [hi|hi|lo], B remap [hi|lo|hi]).
// MODE 2: G2 recon: A=h_p, B=w_cat hi, K=1024 -> recon partials (redp), aux=v.
// MODE 3: split-K x8 grad: A,B += z*K cols -> (z<4?f32out:redp)+(z&3)*VH.
// MODE 4: G4 vk: A=hbin (dup), B=w_cat, K=2048 -> vk, vkT, vbm (fused).
// MODE 5: G5 split-K x2 partial: A=vk (dup), B=wT_cat.
template <int MODE>
__global__ __launch_bounds__(512) void gemm256(
    const u16* __restrict__ A, int lda, const u16* __restrict__ Bm, int ldb, int K,
    const float* __restrict__ bias, const float* __restrict__ uni,
    const float* __restrict__ aux, float* __restrict__ f32out,
    u16* __restrict__ bfout, u16* __restrict__ bfout2,
    float* __restrict__ redp, u16* __restrict__ tout, float* __restrict__ colp) {
  constexpr bool TRANS = (MODE == 4);
  constexpr bool PF = (MODE == 2 || MODE == 4);
  // As[4][256][32] at 0 (32768 u16), Bs[4][256][32] at 32768; 128 KB.
  // MODE4 epilogue ebuf [256][264] (67584 u16 = 132 KB) aliases everything.
  __shared__ __align__(16) u16 smem[TRANS ? 67584 : 65536];
  const int t = threadIdx.x;
  const int lane = t & 63, wave = t >> 6;                // 8 waves
  const int wr = (wave >> 2) << 7;                       // 0 / 128
  const int wc = (wave & 3) << 6;                        // 0/64/128/192
  // XCD-chunked bijective blockIdx swizzle [T1]: hw dispatches linear ids
  // round-robin over 8 XCDs; remap so XCD k owns logical ids
  // [k*nwg/8, (k+1)*nwg/8). nwg == 256 for every launch -> bijective.
  int bidx, bidy, bidz;
  {
    const int gx = gridDim.x, gy = gridDim.y;
    const int nwg = gx * gy * gridDim.z;
    const int orig = blockIdx.x + gx * (blockIdx.y + gy * blockIdx.z);
    const int cpx = nwg >> 3;
    const int swz = (orig & 7) * cpx + (orig >> 3);
    bidx = swz % gx;
    const int rq = swz / gx;
    bidy = rq % gy;
    bidz = rq / gy;
  }
  const int bm = bidx << 8, bn = bidy << 8;
  int kbeg = 0;
  float* pout = f32out;
  if constexpr (MODE == 1 || MODE == 5) {
    kbeg = bidz * K;
    pout = (bidz == 0) ? f32out : redp;
  }
  if constexpr (MODE == 3) {
    size_t off = (size_t)bidz * (size_t)K;
    A += off;
    Bm += off;
    pout = ((bidz < 4) ? f32out : redp) + (size_t)(bidz & 3) * VH;
  }
  f32x4 acc[8][4] = {};
  // staging (one gload = 512 thr x 16B = 128 rows x 64B): LDS row sr = t>>2,
  // granule t&3; fetch SWIZZLED global granule (t&3) ^ ((row>>1)&3) [r5 T2].
  const int sr = t >> 2;
  const int sc = (((t & 3) ^ ((t >> 3) & 3)) << 3);
  const u16* Ag  = A  + (size_t)(bm + sr) * lda + sc;
  const u16* Ag2 = Ag + (size_t)128 * lda;
  const u16* Bg  = Bm + (size_t)(bn + sr) * ldb + sc;
  const u16* Bg2 = Bg + (size_t)128 * ldb;
  const int fr = lane & 15, fg = lane >> 4;
  const int ga = ((fg ^ ((fr >> 1) & 3)) << 3);          // swizzled read granule

  auto stage = [&](int kt) {
    const int k0 = kbeg + (kt << 5);
    int acol, bcol;
    if constexpr (MODE == 1) {
      acol = (k0 < 2048) ? k0 : k0 - 2048;               // [hi|hi|lo]
      bcol = (k0 < 4096) ? k0 : k0 - 4096;               // [hi|lo|hi]
    } else if constexpr (MODE == 4) { acol = k0 & 1023; bcol = k0; }
    else if constexpr (MODE == 5)   { acol = k0 & 2047; bcol = k0; }
    else                            { acol = k0;        bcol = k0; }
    const int pb = kt & 3;
    u16* ad = smem + pb * 8192 + wave * 512;             // wave-uniform base
    u16* bd = smem + 32768 + pb * 8192 + wave * 512;
    gload16(Ag + acol, ad);
    gload16(Ag2 + acol, ad + 4096);
    gload16(Bg + bcol, bd);
    gload16(Bg2 + bcol, bd + 4096);
  };
  auto compute = [&](int kt) {
    const int pb = kt & 3;
    const u16* Ab = smem + pb * 8192;
    const u16* Bb = smem + 32768 + pb * 8192;
    s16x8 bf[4], af[4];
#pragma unroll
    for (int n = 0; n < 4; ++n)
      bf[n] = *(const s16x8*)&Bb[(wc + n * 16 + fr) * 32 + ga];
#pragma unroll
    for (int m = 0; m < 4; ++m)
      af[m] = *(const s16x8*)&Ab[(wr + m * 16 + fr) * 32 + ga];
    __builtin_amdgcn_s_setprio(1);
#pragma unroll
    for (int m = 0; m < 4; ++m)
#pragma unroll
      for (int n = 0; n < 4; ++n)
        acc[m][n] = __builtin_amdgcn_mfma_f32_16x16x32_bf16(af[m], bf[n], acc[m][n], 0, 0, 0);
    __builtin_amdgcn_s_setprio(0);
#pragma unroll
    for (int m = 0; m < 4; ++m)
      af[m] = *(const s16x8*)&Ab[(wr + (m + 4) * 16 + fr) * 32 + ga];
    __builtin_amdgcn_s_setprio(1);
#pragma unroll
    for (int m = 0; m < 4; ++m)
#pragma unroll
      for (int n = 0; n < 4; ++n)
        acc[m + 4][n] = __builtin_amdgcn_mfma_f32_16x16x32_bf16(af[m], bf[n], acc[m + 4][n], 0, 0, 0);
    __builtin_amdgcn_s_setprio(0);
  };
  // epilogue-tile L2 prefetch: one f32 probe per 128B L2 line; the [256][256]
  // f32 tile = 2048 lines = 4 chunks x 512 threads.
  auto pfl = [&](int ci) -> float {
    const int L = (ci << 9) + t;         // 0..2047
    const float* pfp = (MODE == 2) ? aux : uni;
    return pfp[(size_t)(bm + (L >> 3)) * Vn + bn + ((L & 7) << 5)];
  };

  // depth-4 pipeline: stage T+3 each iter; vmcnt(8) waits own tile-T loads
  // (12 outstanding -> 8); barrier publishes all waves' slices.
  const int NT = K >> 5;               // >= 32 for all modes
  const int pfbeg = NT - 8;            // 4 chunks at T in [NT-8, NT-4)
  stage(0); stage(1); stage(2);
  int T = 0;
  for (; T < NT - 3; ++T) {
    asm volatile("s_waitcnt vmcnt(8)" ::: "memory");
    __builtin_amdgcn_s_barrier();
    asm volatile("" ::: "memory");
    stage(T + 3);
    if constexpr (PF) {
      if (T >= pfbeg && T < pfbeg + 4) {
        float pfv = pfl(T - pfbeg);
        asm volatile("" :: "v"(pfv));
      }
    }
    compute(T);
  }
  asm volatile("s_waitcnt vmcnt(8)" ::: "memory");
  __builtin_amdgcn_s_barrier();
  asm volatile("" ::: "memory");
  compute(T++);
  asm volatile("s_waitcnt vmcnt(4)" ::: "memory");
  __builtin_amdgcn_s_barrier();
  asm volatile("" ::: "memory");
  compute(T++);
  asm volatile("s_waitcnt vmcnt(0)" ::: "memory");
  __builtin_amdgcn_s_barrier();
  asm volatile("" ::: "memory");
  compute(T);

  // ---- epilogue ----
  constexpr int NC = (MODE == 2 || MODE == 4) ? Vn : Hn;
  const int fq = lane >> 4;

  if constexpr (MODE == 1 || MODE == 3 || MODE == 5) {
#pragma unroll
    for (int m = 0; m < 8; ++m)
#pragma unroll
      for (int n = 0; n < 4; ++n)
#pragma unroll
        for (int j = 0; j < 4; ++j) {
          int rl = wr + m * 16 + fq * 4 + j;
          int cl = wc + n * 16 + fr;
          pout[(size_t)(bm + rl) * NC + bn + cl] = acc[m][n][j];
        }
  }

  if constexpr (MODE == 2) {
    // two-phase pipelined recon: issue 8 chunk loads -> sigmoid in place
    // (hides latency; aux tile is L2-warm from the main-loop prefetch) ->
    // depth-8 rolling-window consume. Static indices only (ax[ci&7]).
    float bcol[4];
#pragma unroll
    for (int n = 0; n < 4; ++n) bcol[n] = bias[bn + wc + n * 16 + fr];
    const size_t ebase = (size_t)(bm + wr + fq * 4) * NC + (bn + wc + fr);
    float ax[8][4];
    auto ld4 = [&](int ci, float* dst) {
      size_t e0 = ebase + (size_t)((ci >> 2) << 4) * NC + ((ci & 3) << 4);
      dst[0] = aux[e0];          dst[1] = aux[e0 + NC];
      dst[2] = aux[e0 + 2 * NC]; dst[3] = aux[e0 + 3 * NC];
    };
#pragma unroll
    for (int ci = 0; ci < 8; ++ci) ld4(ci, ax[ci]);
#pragma unroll
    for (int m = 0; m < 8; ++m)
#pragma unroll
      for (int n = 0; n < 4; ++n)
#pragma unroll
        for (int j = 0; j < 4; ++j)
          acc[m][n][j] = sigmoidf_(acc[m][n][j] + bcol[n]);
    float lsum = 0.f;
#pragma unroll
    for (int ci = 0; ci < 32; ++ci) {
      const int m = ci >> 2, n = ci & 3;
#pragma unroll
      for (int j = 0; j < 4; ++j) lsum += fabsf(ax[ci & 7][j] - acc[m][n][j]);
      if (ci < 24) ld4(ci + 8, ax[ci & 7]);
    }
#pragma unroll
    for (int off = 32; off > 0; off >>= 1) lsum += __shfl_down(lsum, off);
    __syncthreads();
    float* redlds = (float*)smem;
    if (lane == 0) redlds[wave] = lsum;
    __syncthreads();
    if (t == 0) {
      float s = 0.f;
#pragma unroll
      for (int wv = 0; wv < 8; ++wv) s += redlds[wv];
      redp[(size_t)bidy * gridDim.x + bidx] = s;
    }
  }

  if constexpr (MODE == 4) {
    __syncthreads();   // all waves done with dbuf before ebuf writes
    float bcol[4];
#pragma unroll
    for (int n = 0; n < 4; ++n) bcol[n] = bias[bn + wc + n * 16 + fr];
    const size_t ebase = (size_t)(bm + wr + fq * 4) * NC + (bn + wc + fr);
    float ux[8][4];
    auto ld4 = [&](int ci, float* dst) {
      size_t e0 = ebase + (size_t)((ci >> 2) << 4) * NC + ((ci & 3) << 4);
      dst[0] = uni[e0];          dst[1] = uni[e0 + NC];
      dst[2] = uni[e0 + 2 * NC]; dst[3] = uni[e0 + 3 * NC];
    };
#pragma unroll
    for (int ci = 0; ci < 8; ++ci) ld4(ci, ux[ci]);
#pragma unroll
    for (int m = 0; m < 8; ++m)
#pragma unroll
      for (int n = 0; n < 4; ++n)
#pragma unroll
        for (int j = 0; j < 4; ++j)
          acc[m][n][j] = sigmoidf_(acc[m][n][j] + bcol[n]);
    float csum[4] = {0.f, 0.f, 0.f, 0.f};
#pragma unroll
    for (int ci = 0; ci < 32; ++ci) {
      const int m = ci >> 2, n = ci & 3;
      const int rl = wr + m * 16 + fq * 4;
      const int cl = wc + n * 16 + fr;
#pragma unroll
      for (int j = 0; j < 4; ++j) {
        u16 qb = (acc[m][n][j] > ux[ci & 7][j]) ? (u16)0x3F80 : (u16)0;
        smem[(rl + j) * 264 + cl] = qb;          // ebuf (feeds vk AND vkT)
        csum[n] += (qb ? 1.f : 0.f);
      }
      if (ci < 24) ld4(ci + 8, ux[ci & 7]);
    }
    // vbm partials: lane covers 32 rows; xor16+xor32 reduces fq -> 128 rows
#pragma unroll
    for (int n = 0; n < 4; ++n) {
      float s = csum[n];
      s += __shfl_xor(s, 16);
      s += __shfl_xor(s, 32);
      if (fq == 0)
        colp[(size_t)(bidx * 2 + (wr >> 7)) * NC + (bn + wc + n * 16 + fr)] = s;
    }
    __syncthreads();   // ebuf fully written
    // vk row-major writeout: coalesced u16x8 from ebuf. 256 rows x 32
    // col-chunks = 8192 tasks / 512 thr; consecutive threads fill one row.
#pragma unroll
    for (int it = 0; it < 16; ++it) {
      int id = t + (it << 9);
      int r = id >> 5;                   // 0..255
      int c0 = (id & 31) << 3;           // 0..248
      u16x8 pk = *(const u16x8*)&smem[r * 264 + c0];
      *(u16x8*)&bfout[(size_t)(bm + r) * NC + bn + c0] = pk;
    }
    // transposed write-out: 256 cols x 32 row-groups(8) = 8192 tasks / 512 thr
#pragma unroll
    for (int it = 0; it < 16; ++it) {
      int id = t + (it << 9);
      int c = id & 255;
      int rg2 = id >> 8;                 // 0..31
      u16x8 pk;
#pragma unroll
      for (int i2 = 0; i2 < 8; ++i2) pk[i2] = smem[(rg2 * 8 + i2) * 264 + c];
      *(u16x8*)&tout[(size_t)(bn + c) * Bn + bm + rg2 * 8] = pk;
    }
  }
}

// out[i] = sum_{z<8} p[z][i]  (scalar stores: out base misaligned)
__global__ void reduce8_k(const float* __restrict__ p, float* __restrict__ out) {
  size_t e = ((size_t)blockIdx.x * 256 + threadIdx.x) * 4;
  f32x4 r = {};
#pragma unroll
  for (int z = 0; z < 8; ++z) r += *(const f32x4*)&p[(size_t)z * VH + e];
  out[e + 0] = r[0]; out[e + 1] = r[1]; out[e + 2] = r[2]; out[e + 3] = r[3];
}

// out[i] = sum_{z<4} pa[z][i] + sum_{z<4} pb[z][i] - sub[i]   (w_grad final)
__global__ void reduce8s_k(const float* __restrict__ pa, const float* __restrict__ pb,
                           const float* __restrict__ sub, float* __restrict__ out) {
  size_t e = ((size_t)blockIdx.x * 256 + threadIdx.x) * 4;
  f32x4 r = {};
#pragma unroll
  for (int z = 0; z < 4; ++z) r += *(const f32x4*)&pa[(size_t)z * VH + e];
#pragma unroll
  for (int z = 0; z < 4; ++z) r += *(const f32x4*)&pb[(size_t)z * VH + e];
  float s0 = sub[e + 0], s1 = sub[e + 1], s2 = sub[e + 2], s3 = sub[e + 3];
  out[e + 0] = r[0] - s0; out[e + 1] = r[1] - s1;
  out[e + 2] = r[2] - s2; out[e + 3] = r[3] - s3;
}

// final reductions: bias grads + recon scalar
// vbd:128 part., hbd:128, vbm:64, hbm:128, recon:256
__global__ void finalize_k(const float* __restrict__ sums, float* __restrict__ out) {
  int i = blockIdx.x * 256 + threadIdx.x;
  const float* recon_p = sums;                 // 256
  const float* vbd = sums + 1024;              // 128 x 2048
  const float* hbd = vbd + 128 * 2048;         // 128 x 1024
  const float* vbm = hbd + 128 * 1024;         // 64 x 2048
  const float* hbm = vbm + 128 * 2048;         // 128 x 1024
  if (i < 2048) {
    float d = 0.f, m = 0.f;
    for (int k = 0; k < 128; ++k) d += vbd[k * 2048 + i];
    for (int k = 0; k < 64; ++k)  m += vbm[k * 2048 + i];
    out[OUT_VBG + i] = m - d;
  }
  if (i < 1024) {
    float d = 0.f, m = 0.f;
    for (int k = 0; k < 128; ++k) { d += hbd[k * 1024 + i]; m += hbm[k * 1024 + i]; }
    out[OUT_HBG + i] = m - d;
  }
  if (i == 0) {
    float s = 0.f;
    for (int k = 0; k < 256; ++k) s += recon_p[k];
    out[OUT_RECON] = s * (1.0f / 16777216.0f);  // /(B*V)
  }
}

extern "C" void kernel_launch(void* const* d_in, const int* in_sizes, int n_in,
                              void* d_out, int out_size, void* d_ws, size_t ws_size,
                              hipStream_t stream) {
  (void)in_sizes; (void)n_in; (void)out_size;
  const float* v   = (const float*)d_in[0];
  const float* w   = (const float*)d_in[1];
  const float* vb  = (const float*)d_in[2];
  const float* hb  = (const float*)d_in[3];
  const float* u_h = (const float*)d_in[4];
  const float* u_v = (const float*)d_in[5];
  float* out = (float*)d_out;
  char* ws = (char*)d_ws;
  if (ws_size < 204734464ULL) return;

  float* sums    = (float*)ws;               // 3.25 MiB region
  float* recon_p = sums;                     // 256
  float* vbd_p   = sums + 1024;              // 128*2048
  float* hbd_p   = vbd_p + 128 * 2048;       // 128*1024
  float* vbm_p   = hbd_p + 128 * 1024;       // 64*2048
  float* hbm_p   = vbm_p + 128 * 2048;       // 128*1024
  char* p = ws + 3407872;
  u16* v_cat  = (u16*)p;  p += (size_t)Bn * 2 * Vn * 2;   // 64 MiB [B,2V]
  u16* wT_cat = (u16*)p;  p += (size_t)Hn * 2 * Vn * 2;   // 8 MiB [H,2V]
  u16* w_cat  = (u16*)p;  p += (size_t)Vn * 2 * Hn * 2;   // 8 MiB [V,2H]
  u16* h_p    = (u16*)p;  p += BH * 2;                    // 16 MiB [B,H]
  u16* hbin   = (u16*)p;  p += BH * 2;                    // 16 MiB [B,H]
  u16* vT     = (u16*)p;  p += (size_t)Vn * Bn * 2;       // 32 MiB [V,B]
  u16* hT     = (u16*)p;  p += (size_t)Hn * Bn * 2;       // 16 MiB [H,B]
  float* big  = (float*)p;                                // 32 MiB time-shared
  u16* vk   = v_cat;            // v_cat dead after G1a
  u16* vkT  = vT;               // vT dead after G3
  u16* h2T  = hT;               // hT dead after G3
  float* vcat_f = (float*)v_cat;   // 64 MiB: G3's 8 partials (v_cat dead then)
  float* hpbuf  = (float*)h_p;     // h_p+hbin region (32 MiB) as f32 partials
  float* outW   = out + OUT_WGRAD;

  prep_vt_k<<<dim3(Bn / 64, Vn / 64), 256, 0, stream>>>(v, v_cat, vT, vbd_p);
  prep_w_k<<<dim3(Vn / 64, Hn / 64), 256, 0, stream>>>(w, w_cat, wT_cat);
  // G1a: split-K x2 partials (z0 -> out[0..BH) scratch, z1 -> big)
  gemm256<1><<<dim3(32, 4, 2), 512, 0, stream>>>(
      v_cat, 2 * Vn, wT_cat, 2 * Vn, 3072, nullptr, nullptr, nullptr,
      out, nullptr, nullptr, big, nullptr, nullptr);
  // epi: h_pred / h_p / hbin / hT / hbd
  epi_h_k<1><<<dim3(128, 16), 256, 0, stream>>>(
      out, big, hb, u_h, out, h_p, hbin, hT, hbd_p);
  // G2: recon partials (256 blocks)
  gemm256<2><<<dim3(32, 8), 512, 0, stream>>>(
      h_p, Hn, w_cat, 2 * Hn, Hn, vb, nullptr, v,
      nullptr, nullptr, nullptr, recon_p, nullptr, nullptr);
  // G3: w_data_grad partials (split-K x8 -> v_cat region, 64 MiB)
  gemm256<3><<<dim3(Vn / 256, Hn / 256, 8), 512, 0, stream>>>(
      vT, Bn, hT, Bn, 1024, nullptr, nullptr, nullptr,
      vcat_f, nullptr, nullptr, vcat_f + 4 * VH, nullptr, nullptr);
  reduce8_k<<<2048, 256, 0, stream>>>(vcat_f, outW);   // outW = data-grad sum
  // G4: vk/vkT + vbm partials (fused sample+transpose epilogue)
  gemm256<4><<<dim3(32, 8), 512, 0, stream>>>(
      hbin, Hn, w_cat, 2 * Hn, 2 * Hn, vb, u_v, nullptr,
      nullptr, vk, nullptr, nullptr, vkT, vbm_p);
  // G5a: split-K x2 partials (z0 -> hpbuf, z1 -> big); h_p/hbin dead now
  gemm256<5><<<dim3(32, 4, 2), 512, 0, stream>>>(
      vk, Vn, wT_cat, 2 * Vn, 2048, nullptr, nullptr, nullptr,
      hpbuf, nullptr, nullptr, big, nullptr, nullptr);
  // epi: h2T + hbm
  epi_h_k<5><<<dim3(128, 16), 256, 0, stream>>>(
      hpbuf, big, hb, u_h + BH, nullptr, nullptr, nullptr, h2T, hbm_p);
  // G6: w_model_grad partials (split-K x8: z<4 -> hpbuf, z>=4 -> big)
  gemm256<3><<<dim3(Vn / 256, Hn / 256, 8), 512, 0, stream>>>(
      vkT, Bn, h2T, Bn, 1024, nullptr, nullptr, nullptr,
      hpbuf, nullptr, nullptr, big, nullptr, nullptr);
  reduce8s_k<<<2048, 256, 0, stream>>>(hpbuf, big, outW, outW);  // model - data
  finalize_k<<<8, 256, 0, stream>>>(sums, out);
}

// Round 5
// 526.369 us; speedup vs baseline: 1.0542x; 1.0542x over previous
//
#include <hip/hip_runtime.h>

// RBM CD-1 step on MI355X — round 13.
// = round-11 kernel (verified 528.6us) + MODE-3-ONLY XCD swizzle.
// r12 lesson (FETCH 114->203MB, +26us): chunk-of-32 remap gave each XCD all
// 32 M-panels x 1 N-panel -> full-A refetch per XCD. It also CONFIRMED
// XCD = linear_block_id % 8. For MODE 3 (grid 8x4x8, z = split-K slice) the
// winning shape is XCD k <-> z-slice k: each XCD reads its own 4MB A-slice +
// 2MB B-slice once (6MB/XCD vs 20MB/XCD linear). Other modes keep the
// hardware-linear mapping (bidx%8 = XCD -> only 4 A-panels/XCD, already the
// better shape per r12's measurement).

typedef unsigned short u16;
typedef short s16x8 __attribute__((ext_vector_type(8)));
typedef float f32x4 __attribute__((ext_vector_type(4)));
typedef u16 u16x4 __attribute__((ext_vector_type(4)));
typedef u16 u16x8 __attribute__((ext_vector_type(8)));

constexpr int Bn = 8192, Vn = 2048, Hn = 1024;
constexpr size_t VH = (size_t)Vn * Hn;
constexpr size_t BH = (size_t)Bn * Hn;
constexpr size_t OUT_RECON = BH;                        // 8388608
constexpr size_t OUT_WGRAD = OUT_RECON + 1;             // 8388609
constexpr size_t OUT_VBG   = OUT_WGRAD + VH;            // 10485761
constexpr size_t OUT_HBG   = OUT_VBG + Vn;              // 10487809

__device__ __forceinline__ u16 f2bf(float x) {
  union { float f; unsigned u; } a; a.f = x;
  unsigned r = a.u + 0x7FFFu + ((a.u >> 16) & 1u);   // RNE
  return (u16)(r >> 16);
}
__device__ __forceinline__ float bf2f(u16 h) {
  union { unsigned u; float f; } a; a.u = ((unsigned)h) << 16;
  return a.f;
}
__device__ __forceinline__ float sigmoidf_(float x) {
  return 1.0f / (1.0f + __expf(-x));
}

using gptr_t = const unsigned int __attribute__((address_space(1)))*;
using lptr_t = unsigned int __attribute__((address_space(3)))*;

__device__ __forceinline__ void gload16(const u16* g, u16* l) {
  __builtin_amdgcn_global_load_lds((gptr_t)(unsigned long long)g,
                                   (lptr_t)(unsigned long long)l, 16, 0, 0);
}

// ---------------- prep kernels ----------------

// v[B,V] f32 -> v_cat[B,2V]=[hi|lo], vT[V,B] (hi, transposed), vbd partials.
__global__ void prep_vt_k(const float* __restrict__ v, u16* __restrict__ vcat,
                          u16* __restrict__ vT, float* __restrict__ vbd_p) {
  __shared__ u16 tile[64][68];
  __shared__ float cs[16][64];
  const int b0 = blockIdx.x * 64, c0 = blockIdx.y * 64;
  const int t = threadIdx.x;
  const int rg = t >> 4;          // 0..15 row group
  const int cg = (t & 15) << 2;   // col *4
  float ca[4] = {0.f, 0.f, 0.f, 0.f};
#pragma unroll
  for (int i = 0; i < 4; ++i) {
    int r = rg + 16 * i;
    f32x4 x = *(const f32x4*)&v[(size_t)(b0 + r) * Vn + c0 + cg];
    u16x4 hi, lo;
#pragma unroll
    for (int j = 0; j < 4; ++j) {
      hi[j] = f2bf(x[j]);
      lo[j] = f2bf(x[j] - bf2f(hi[j]));
      tile[r][cg + j] = hi[j];
      ca[j] += x[j];
    }
    *(u16x4*)&vcat[(size_t)(b0 + r) * (2 * Vn) + c0 + cg] = hi;
    *(u16x4*)&vcat[(size_t)(b0 + r) * (2 * Vn) + Vn + c0 + cg] = lo;
  }
#pragma unroll
  for (int j = 0; j < 4; ++j) cs[rg][cg + j] = ca[j];
  __syncthreads();
  if (t < 64) {
    float s = 0.f;
#pragma unroll
    for (int k = 0; k < 16; ++k) s += cs[k][t];
    vbd_p[(size_t)blockIdx.x * Vn + c0 + t] = s;   // [128][2048]
  }
#pragma unroll
  for (int s2 = 0; s2 < 2; ++s2) {
    int c = t >> 2;
    int seg = (t & 3) + 4 * s2;
    u16x8 pk;
#pragma unroll
    for (int i = 0; i < 8; ++i) pk[i] = tile[seg * 8 + i][c];
    *(u16x8*)&vT[(size_t)(c0 + c) * Bn + b0 + seg * 8] = pk;
  }
}

// w[V,H] f32 -> w_cat[V,2H]=[hi|lo] and wT_cat[H,2V]=[hi|lo] (transposed)
__global__ void prep_w_k(const float* __restrict__ w, u16* __restrict__ w_cat,
                         u16* __restrict__ wTc) {
  __shared__ float tile[64][65];
  int v0 = blockIdx.x * 64, h0 = blockIdx.y * 64;
  int t = threadIdx.x, c = t & 63, r = t >> 6;
  for (int rr = r; rr < 64; rr += 4) {
    float x = w[(size_t)(v0 + rr) * Hn + h0 + c];
    tile[rr][c] = x;
    u16 hi = f2bf(x), lo = f2bf(x - bf2f(hi));
    w_cat[(size_t)(v0 + rr) * (2 * Hn) + h0 + c]      = hi;
    w_cat[(size_t)(v0 + rr) * (2 * Hn) + Hn + h0 + c] = lo;
  }
  __syncthreads();
  for (int rr = r; rr < 64; rr += 4) {
    float x = tile[c][rr];  // = w[v0+c][h0+rr]
    u16 hi = f2bf(x), lo = f2bf(x - bf2f(hi));
    size_t ro = (size_t)(h0 + rr) * (2 * Vn);
    wTc[ro + v0 + c]      = hi;
    wTc[ro + Vn + v0 + c] = lo;
  }
}

// ---- sampling epilogue for split-K [B,H] pre-activations ----------------
template <int M>
__global__ void epi_h_k(const float* __restrict__ p0, const float* __restrict__ p1,
                        const float* __restrict__ bias, const float* __restrict__ uni,
                        float* __restrict__ f32out, u16* __restrict__ hp_out,
                        u16* __restrict__ hbin_out, u16* __restrict__ tout,
                        float* __restrict__ colp) {
  __shared__ u16 tile[64][68];
  __shared__ float cs[16][64];
  const int b0 = blockIdx.x * 64, c0 = blockIdx.y * 64;
  const int t = threadIdx.x;
  const int rg = t >> 4, cg = (t & 15) << 2;
  float ca[4] = {0.f, 0.f, 0.f, 0.f};
#pragma unroll
  for (int i = 0; i < 4; ++i) {
    int r = rg + 16 * i;
    size_t e = (size_t)(b0 + r) * Hn + c0 + cg;
    f32x4 a = *(const f32x4*)&p0[e];
    f32x4 b = *(const f32x4*)&p1[e];
    f32x4 uu = *(const f32x4*)&uni[e];
    f32x4 hpv;
    u16x4 hb16, qv;
#pragma unroll
    for (int j = 0; j < 4; ++j) {
      float hp = sigmoidf_(a[j] + b[j] + bias[c0 + cg + j]);
      u16 qb = (hp > uu[j]) ? (u16)0x3F80 : (u16)0;
      tile[r][cg + j] = qb;
      if constexpr (M == 1) {
        hpv[j] = hp; hb16[j] = f2bf(hp); qv[j] = qb;
        ca[j] += hp;
      } else {
        ca[j] += (qb ? 1.f : 0.f);
      }
    }
    if constexpr (M == 1) {
      *(f32x4*)&f32out[e] = hpv;        // h_prediction (overwrites p0 region)
      *(u16x4*)&hp_out[e] = hb16;
      *(u16x4*)&hbin_out[e] = qv;
    }
  }
#pragma unroll
  for (int j = 0; j < 4; ++j) cs[rg][cg + j] = ca[j];
  __syncthreads();
  if (t < 64) {
    float s = 0.f;
#pragma unroll
    for (int k = 0; k < 16; ++k) s += cs[k][t];
    colp[(size_t)blockIdx.x * Hn + c0 + t] = s;   // [128][1024]
  }
#pragma unroll
  for (int s2 = 0; s2 < 2; ++s2) {
    int c = t >> 2;
    int seg = (t & 3) + 4 * s2;
    u16x8 pk;
#pragma unroll
    for (int i = 0; i < 8; ++i) pk[i] = tile[seg * 8 + i][c];
    *(u16x8*)&tout[(size_t)(c0 + c) * Bn + b0 + seg * 8] = pk;
  }
}

// ---------------- GEMM 256x256, BK=32, 8 waves, depth-4 counted pipeline --
// MODE 1: G1 split-K x2 partial (A remap [hi|hi|lo], B remap [hi|lo|hi]).
// MODE 2: G2 recon: A=h_p, B=w_cat hi, K=1024 -> recon partials (redp), aux=v.
// MODE 3: split-K x8 grad: A,B += z*K cols -> (z<4?f32out:redp)+(z&3)*VH.
// MODE 4: G4 vk: A=hbin (dup), B=w_cat, K=2048 -> vk, vkT, vbm (fused).
// MODE 5: G5 split-K x2 partial: A=vk (dup), B=wT_cat.
template <int MODE>
__global__ __launch_bounds__(512) void gemm256(
    const u16* __restrict__ A, int lda, const u16* __restrict__ Bm, int ldb, int K,
    const float* __restrict__ bias, const float* __restrict__ uni,
    const float* __restrict__ aux, float* __restrict__ f32out,
    u16* __restrict__ bfout, u16* __restrict__ bfout2,
    float* __restrict__ redp, u16* __restrict__ tout, float* __restrict__ colp) {
  constexpr bool TRANS = (MODE == 4);
  constexpr bool PF = (MODE == 2 || MODE == 4);
  // As[4][256][32] at 0 (32768 u16), Bs[4][256][32] at 32768; 128 KB.
  // MODE4 epilogue ebuf [256][264] (67584 u16 = 132 KB) aliases everything.
  __shared__ __align__(16) u16 smem[TRANS ? 67584 : 65536];
  const int t = threadIdx.x;
  const int lane = t & 63, wave = t >> 6;                // 8 waves
  const int wr = (wave >> 2) << 7;                       // 0 / 128
  const int wc = (wave & 3) << 6;                        // 0/64/128/192
  // MODE-3-only XCD swizzle: grid (8,4,8), z = K-slice. HW: XCD = linear%8
  // (confirmed r12). Remap so XCD k owns z-slice k's full 8x4 MxN grid:
  // per-XCD L2-miss traffic 20MB -> 6MB. Bijective on 256 blocks.
  int bidx = blockIdx.x, bidy = blockIdx.y, bidz = blockIdx.z;
  if constexpr (MODE == 3) {
    const int orig = blockIdx.x + (blockIdx.y << 3) + (blockIdx.z << 5);
    bidz = orig & 7;
    const int r = orig >> 3;       // 0..31 rank within XCD
    bidx = r & 7;
    bidy = r >> 3;
  }
  const int bm = bidx << 8, bn = bidy << 8;
  int kbeg = 0;
  float* pout = f32out;
  if constexpr (MODE == 1 || MODE == 5) {
    kbeg = bidz * K;
    pout = (bidz == 0) ? f32out : redp;
  }
  if constexpr (MODE == 3) {
    size_t off = (size_t)bidz * (size_t)K;
    A += off;
    Bm += off;
    pout = ((bidz < 4) ? f32out : redp) + (size_t)(bidz & 3) * VH;
  }
  f32x4 acc[8][4] = {};
  // staging (one gload = 512 thr x 16B = 128 rows x 64B): LDS row sr = t>>2,
  // granule t&3; fetch SWIZZLED global granule (t&3) ^ ((row>>1)&3) [r5 T2].
  const int sr = t >> 2;
  const int sc = (((t & 3) ^ ((t >> 3) & 3)) << 3);
  const u16* Ag  = A  + (size_t)(bm + sr) * lda + sc;
  const u16* Ag2 = Ag + (size_t)128 * lda;
  const u16* Bg  = Bm + (size_t)(bn + sr) * ldb + sc;
  const u16* Bg2 = Bg + (size_t)128 * ldb;
  const int fr = lane & 15, fg = lane >> 4;
  const int ga = ((fg ^ ((fr >> 1) & 3)) << 3);          // swizzled read granule

  auto stage = [&](int kt) {
    const int k0 = kbeg + (kt << 5);
    int acol, bcol;
    if constexpr (MODE == 1) {
      acol = (k0 < 2048) ? k0 : k0 - 2048;               // [hi|hi|lo]
      bcol = (k0 < 4096) ? k0 : k0 - 4096;               // [hi|lo|hi]
    } else if constexpr (MODE == 4) { acol = k0 & 1023; bcol = k0; }
    else if constexpr (MODE == 5)   { acol = k0 & 2047; bcol = k0; }
    else                            { acol = k0;        bcol = k0; }
    const int pb = kt & 3;
    u16* ad = smem + pb * 8192 + wave * 512;             // wave-uniform base
    u16* bd = smem + 32768 + pb * 8192 + wave * 512;
    gload16(Ag + acol, ad);
    gload16(Ag2 + acol, ad + 4096);
    gload16(Bg + bcol, bd);
    gload16(Bg2 + bcol, bd + 4096);
  };
  auto compute = [&](int kt) {
    const int pb = kt & 3;
    const u16* Ab = smem + pb * 8192;
    const u16* Bb = smem + 32768 + pb * 8192;
    s16x8 bf[4], af[4];
#pragma unroll
    for (int n = 0; n < 4; ++n)
      bf[n] = *(const s16x8*)&Bb[(wc + n * 16 + fr) * 32 + ga];
#pragma unroll
    for (int m = 0; m < 4; ++m)
      af[m] = *(const s16x8*)&Ab[(wr + m * 16 + fr) * 32 + ga];
    __builtin_amdgcn_s_setprio(1);
#pragma unroll
    for (int m = 0; m < 4; ++m)
#pragma unroll
      for (int n = 0; n < 4; ++n)
        acc[m][n] = __builtin_amdgcn_mfma_f32_16x16x32_bf16(af[m], bf[n], acc[m][n], 0, 0, 0);
    __builtin_amdgcn_s_setprio(0);
#pragma unroll
    for (int m = 0; m < 4; ++m)
      af[m] = *(const s16x8*)&Ab[(wr + (m + 4) * 16 + fr) * 32 + ga];
    __builtin_amdgcn_s_setprio(1);
#pragma unroll
    for (int m = 0; m < 4; ++m)
#pragma unroll
      for (int n = 0; n < 4; ++n)
        acc[m + 4][n] = __builtin_amdgcn_mfma_f32_16x16x32_bf16(af[m], bf[n], acc[m + 4][n], 0, 0, 0);
    __builtin_amdgcn_s_setprio(0);
  };
  // epilogue-tile L2 prefetch: one f32 probe per 128B L2 line; the [256][256]
  // f32 tile = 2048 lines = 4 chunks x 512 threads.
  auto pfl = [&](int ci) -> float {
    const int L = (ci << 9) + t;         // 0..2047
    const float* pfp = (MODE == 2) ? aux : uni;
    return pfp[(size_t)(bm + (L >> 3)) * Vn + bn + ((L & 7) << 5)];
  };

  // depth-4 pipeline: stage T+3 each iter; vmcnt(8) waits own tile-T loads
  // (12 outstanding -> 8); barrier publishes all waves' slices.
  const int NT = K >> 5;               // >= 32 for all modes
  const int pfbeg = NT - 8;            // 4 chunks at T in [NT-8, NT-4)
  stage(0); stage(1); stage(2);
  int T = 0;
  for (; T < NT - 3; ++T) {
    asm volatile("s_waitcnt vmcnt(8)" ::: "memory");
    __builtin_amdgcn_s_barrier();
    asm volatile("" ::: "memory");
    stage(T + 3);
    if constexpr (PF) {
      if (T >= pfbeg && T < pfbeg + 4) {
        float pfv = pfl(T - pfbeg);
        asm volatile("" :: "v"(pfv));
      }
    }
    compute(T);
  }
  asm volatile("s_waitcnt vmcnt(8)" ::: "memory");
  __builtin_amdgcn_s_barrier();
  asm volatile("" ::: "memory");
  compute(T++);
  asm volatile("s_waitcnt vmcnt(4)" ::: "memory");
  __builtin_amdgcn_s_barrier();
  asm volatile("" ::: "memory");
  compute(T++);
  asm volatile("s_waitcnt vmcnt(0)" ::: "memory");
  __builtin_amdgcn_s_barrier();
  asm volatile("" ::: "memory");
  compute(T);

  // ---- epilogue ----
  constexpr int NC = (MODE == 2 || MODE == 4) ? Vn : Hn;
  const int fq = lane >> 4;

  if constexpr (MODE == 1 || MODE == 3 || MODE == 5) {
#pragma unroll
    for (int m = 0; m < 8; ++m)
#pragma unroll
      for (int n = 0; n < 4; ++n)
#pragma unroll
        for (int j = 0; j < 4; ++j) {
          int rl = wr + m * 16 + fq * 4 + j;
          int cl = wc + n * 16 + fr;
          pout[(size_t)(bm + rl) * NC + bn + cl] = acc[m][n][j];
        }
  }

  if constexpr (MODE == 2) {
    // two-phase pipelined recon: issue 8 chunk loads -> sigmoid in place
    // (hides latency; aux tile is L2-warm from the main-loop prefetch) ->
    // depth-8 rolling-window consume. Static indices only (ax[ci&7]).
    float bcol[4];
#pragma unroll
    for (int n = 0; n < 4; ++n) bcol[n] = bias[bn + wc + n * 16 + fr];
    const size_t ebase = (size_t)(bm + wr + fq * 4) * NC + (bn + wc + fr);
    float ax[8][4];
    auto ld4 = [&](int ci, float* dst) {
      size_t e0 = ebase + (size_t)((ci >> 2) << 4) * NC + ((ci & 3) << 4);
      dst[0] = aux[e0];          dst[1] = aux[e0 + NC];
      dst[2] = aux[e0 + 2 * NC]; dst[3] = aux[e0 + 3 * NC];
    };
#pragma unroll
    for (int ci = 0; ci < 8; ++ci) ld4(ci, ax[ci]);
#pragma unroll
    for (int m = 0; m < 8; ++m)
#pragma unroll
      for (int n = 0; n < 4; ++n)
#pragma unroll
        for (int j = 0; j < 4; ++j)
          acc[m][n][j] = sigmoidf_(acc[m][n][j] + bcol[n]);
    float lsum = 0.f;
#pragma unroll
    for (int ci = 0; ci < 32; ++ci) {
      const int m = ci >> 2, n = ci & 3;
#pragma unroll
      for (int j = 0; j < 4; ++j) lsum += fabsf(ax[ci & 7][j] - acc[m][n][j]);
      if (ci < 24) ld4(ci + 8, ax[ci & 7]);
    }
#pragma unroll
    for (int off = 32; off > 0; off >>= 1) lsum += __shfl_down(lsum, off);
    __syncthreads();
    float* redlds = (float*)smem;
    if (lane == 0) redlds[wave] = lsum;
    __syncthreads();
    if (t == 0) {
      float s = 0.f;
#pragma unroll
      for (int wv = 0; wv < 8; ++wv) s += redlds[wv];
      redp[(size_t)blockIdx.y * gridDim.x + blockIdx.x] = s;
    }
  }

  if constexpr (MODE == 4) {
    __syncthreads();   // all waves done with dbuf before ebuf writes
    float bcol[4];
#pragma unroll
    for (int n = 0; n < 4; ++n) bcol[n] = bias[bn + wc + n * 16 + fr];
    const size_t ebase = (size_t)(bm + wr + fq * 4) * NC + (bn + wc + fr);
    float ux[8][4];
    auto ld4 = [&](int ci, float* dst) {
      size_t e0 = ebase + (size_t)((ci >> 2) << 4) * NC + ((ci & 3) << 4);
      dst[0] = uni[e0];          dst[1] = uni[e0 + NC];
      dst[2] = uni[e0 + 2 * NC]; dst[3] = uni[e0 + 3 * NC];
    };
#pragma unroll
    for (int ci = 0; ci < 8; ++ci) ld4(ci, ux[ci]);
#pragma unroll
    for (int m = 0; m < 8; ++m)
#pragma unroll
      for (int n = 0; n < 4; ++n)
#pragma unroll
        for (int j = 0; j < 4; ++j)
          acc[m][n][j] = sigmoidf_(acc[m][n][j] + bcol[n]);
    float csum[4] = {0.f, 0.f, 0.f, 0.f};
#pragma unroll
    for (int ci = 0; ci < 32; ++ci) {
      const int m = ci >> 2, n = ci & 3;
      const int rl = wr + m * 16 + fq * 4;
      const int cl = wc + n * 16 + fr;
#pragma unroll
      for (int j = 0; j < 4; ++j) {
        u16 qb = (acc[m][n][j] > ux[ci & 7][j]) ? (u16)0x3F80 : (u16)0;
        smem[(rl + j) * 264 + cl] = qb;          // ebuf (feeds vk AND vkT)
        csum[n] += (qb ? 1.f : 0.f);
      }
      if (ci < 24) ld4(ci + 8, ux[ci & 7]);
    }
    // vbm partials: lane covers 32 rows; xor16+xor32 reduces fq -> 128 rows
#pragma unroll
    for (int n = 0; n < 4; ++n) {
      float s = csum[n];
      s += __shfl_xor(s, 16);
      s += __shfl_xor(s, 32);
      if (fq == 0)
        colp[(size_t)(blockIdx.x * 2 + (wr >> 7)) * NC + (bn + wc + n * 16 + fr)] = s;
    }
    __syncthreads();   // ebuf fully written
    // vk row-major writeout: coalesced u16x8 from ebuf. 256 rows x 32
    // col-chunks = 8192 tasks / 512 thr; consecutive threads fill one row.
#pragma unroll
    for (int it = 0; it < 16; ++it) {
      int id = t + (it << 9);
      int r = id >> 5;                   // 0..255
      int c0 = (id & 31) << 3;           // 0..248
      u16x8 pk = *(const u16x8*)&smem[r * 264 + c0];
      *(u16x8*)&bfout[(size_t)(bm + r) * NC + bn + c0] = pk;
    }
    // transposed write-out: 256 cols x 32 row-groups(8) = 8192 tasks / 512 thr
#pragma unroll
    for (int it = 0; it < 16; ++it) {
      int id = t + (it << 9);
      int c = id & 255;
      int rg2 = id >> 8;                 // 0..31
      u16x8 pk;
#pragma unroll
      for (int i2 = 0; i2 < 8; ++i2) pk[i2] = smem[(rg2 * 8 + i2) * 264 + c];
      *(u16x8*)&tout[(size_t)(bn + c) * Bn + bm + rg2 * 8] = pk;
    }
  }
}

// out[i] = sum_{z<8} p[z][i]  (scalar stores: out base misaligned)
__global__ void reduce8_k(const float* __restrict__ p, float* __restrict__ out) {
  size_t e = ((size_t)blockIdx.x * 256 + threadIdx.x) * 4;
  f32x4 r = {};
#pragma unroll
  for (int z = 0; z < 8; ++z) r += *(const f32x4*)&p[(size_t)z * VH + e];
  out[e + 0] = r[0]; out[e + 1] = r[1]; out[e + 2] = r[2]; out[e + 3] = r[3];
}

// out[i] = sum_{z<4} pa[z][i] + sum_{z<4} pb[z][i] - sub[i]   (w_grad final)
__global__ void reduce8s_k(const float* __restrict__ pa, const float* __restrict__ pb,
                           const float* __restrict__ sub, float* __restrict__ out) {
  size_t e = ((size_t)blockIdx.x * 256 + threadIdx.x) * 4;
  f32x4 r = {};
#pragma unroll
  for (int z = 0; z < 4; ++z) r += *(const f32x4*)&pa[(size_t)z * VH + e];
#pragma unroll
  for (int z = 0; z < 4; ++z) r += *(const f32x4*)&pb[(size_t)z * VH + e];
  float s0 = sub[e + 0], s1 = sub[e + 1], s2 = sub[e + 2], s3 = sub[e + 3];
  out[e + 0] = r[0] - s0; out[e + 1] = r[1] - s1;
  out[e + 2] = r[2] - s2; out[e + 3] = r[3] - s3;
}

// final reductions: bias grads + recon scalar
// vbd:128 part., hbd:128, vbm:64, hbm:128, recon:256
__global__ void finalize_k(const float* __restrict__ sums, float* __restrict__ out) {
  int i = blockIdx.x * 256 + threadIdx.x;
  const float* recon_p = sums;                 // 256
  const float* vbd = sums + 1024;              // 128 x 2048
  const float* hbd = vbd + 128 * 2048;         // 128 x 1024
  const float* vbm = hbd + 128 * 1024;         // 64 x 2048
  const float* hbm = vbm + 128 * 2048;         // 128 x 1024
  if (i < 2048) {
    float d = 0.f, m = 0.f;
    for (int k = 0; k < 128; ++k) d += vbd[k * 2048 + i];
    for (int k = 0; k < 64; ++k)  m += vbm[k * 2048 + i];
    out[OUT_VBG + i] = m - d;
  }
  if (i < 1024) {
    float d = 0.f, m = 0.f;
    for (int k = 0; k < 128; ++k) { d += hbd[k * 1024 + i]; m += hbm[k * 1024 + i]; }
    out[OUT_HBG + i] = m - d;
  }
  if (i == 0) {
    float s = 0.f;
    for (int k = 0; k < 256; ++k) s += recon_p[k];
    out[OUT_RECON] = s * (1.0f / 16777216.0f);  // /(B*V)
  }
}

extern "C" void kernel_launch(void* const* d_in, const int* in_sizes, int n_in,
                              void* d_out, int out_size, void* d_ws, size_t ws_size,
                              hipStream_t stream) {
  (void)in_sizes; (void)n_in; (void)out_size;
  const float* v   = (const float*)d_in[0];
  const float* w   = (const float*)d_in[1];
  const float* vb  = (const float*)d_in[2];
  const float* hb  = (const float*)d_in[3];
  const float* u_h = (const float*)d_in[4];
  const float* u_v = (const float*)d_in[5];
  float* out = (float*)d_out;
  char* ws = (char*)d_ws;
  if (ws_size < 204734464ULL) return;

  float* sums    = (float*)ws;               // 3.25 MiB region
  float* recon_p = sums;                     // 256
  float* vbd_p   = sums + 1024;              // 128*2048
  float* hbd_p   = vbd_p + 128 * 2048;       // 128*1024
  float* vbm_p   = hbd_p + 128 * 1024;       // 64*2048
  float* hbm_p   = vbm_p + 128 * 2048;       // 128*1024
  char* p = ws + 3407872;
  u16* v_cat  = (u16*)p;  p += (size_t)Bn * 2 * Vn * 2;   // 64 MiB [B,2V]
  u16* wT_cat = (u16*)p;  p += (size_t)Hn * 2 * Vn * 2;   // 8 MiB [H,2V]
  u16* w_cat  = (u16*)p;  p += (size_t)Vn * 2 * Hn * 2;   // 8 MiB [V,2H]
  u16* h_p    = (u16*)p;  p += BH * 2;                    // 16 MiB [B,H]
  u16* hbin   = (u16*)p;  p += BH * 2;                    // 16 MiB [B,H]
  u16* vT     = (u16*)p;  p += (size_t)Vn * Bn * 2;       // 32 MiB [V,B]
  u16* hT     = (u16*)p;  p += (size_t)Hn * Bn * 2;       // 16 MiB [H,B]
  float* big  = (float*)p;                                // 32 MiB time-shared
  u16* vk   = v_cat;            // v_cat dead after G1a
  u16* vkT  = vT;               // vT dead after G3
  u16* h2T  = hT;               // hT dead after G3
  float* vcat_f = (float*)v_cat;   // 64 MiB: G3's 8 partials (v_cat dead then)
  float* hpbuf  = (float*)h_p;     // h_p+hbin region (32 MiB) as f32 partials
  float* outW   = out + OUT_WGRAD;

  prep_vt_k<<<dim3(Bn / 64, Vn / 64), 256, 0, stream>>>(v, v_cat, vT, vbd_p);
  prep_w_k<<<dim3(Vn / 64, Hn / 64), 256, 0, stream>>>(w, w_cat, wT_cat);
  // G1a: split-K x2 partials (z0 -> out[0..BH) scratch, z1 -> big)
  gemm256<1><<<dim3(32, 4, 2), 512, 0, stream>>>(
      v_cat, 2 * Vn, wT_cat, 2 * Vn, 3072, nullptr, nullptr, nullptr,
      out, nullptr, nullptr, big, nullptr, nullptr);
  // epi: h_pred / h_p / hbin / hT / hbd
  epi_h_k<1><<<dim3(128, 16), 256, 0, stream>>>(
      out, big, hb, u_h, out, h_p, hbin, hT, hbd_p);
  // G2: recon partials (256 blocks)
  gemm256<2><<<dim3(32, 8), 512, 0, stream>>>(
      h_p, Hn, w_cat, 2 * Hn, Hn, vb, nullptr, v,
      nullptr, nullptr, nullptr, recon_p, nullptr, nullptr);
  // G3: w_data_grad partials (split-K x8 -> v_cat region, 64 MiB)
  gemm256<3><<<dim3(Vn / 256, Hn / 256, 8), 512, 0, stream>>>(
      vT, Bn, hT, Bn, 1024, nullptr, nullptr, nullptr,
      vcat_f, nullptr, nullptr, vcat_f + 4 * VH, nullptr, nullptr);
  reduce8_k<<<2048, 256, 0, stream>>>(vcat_f, outW);   // outW = data-grad sum
  // G4: vk/vkT + vbm partials (fused sample+transpose epilogue)
  gemm256<4><<<dim3(32, 8), 512, 0, stream>>>(
      hbin, Hn, w_cat, 2 * Hn, 2 * Hn, vb, u_v, nullptr,
      nullptr, vk, nullptr, nullptr, vkT, vbm_p);
  // G5a: split-K x2 partials (z0 -> hpbuf, z1 -> big); h_p/hbin dead now
  gemm256<5><<<dim3(32, 4, 2), 512, 0, stream>>>(
      vk, Vn, wT_cat, 2 * Vn, 2048, nullptr, nullptr, nullptr,
      hpbuf, nullptr, nullptr, big, nullptr, nullptr);
  // epi: h2T + hbm
  epi_h_k<5><<<dim3(128, 16), 256, 0, stream>>>(
      hpbuf, big, hb, u_h + BH, nullptr, nullptr, nullptr, h2T, hbm_p);
  // G6: w_model_grad partials (split-K x8: z<4 -> hpbuf, z>=4 -> big)
  gemm256<3><<<dim3(Vn / 256, Hn / 256, 8), 512, 0, stream>>>(
      vkT, Bn, h2T, Bn, 1024, nullptr, nullptr, nullptr,
      hpbuf, nullptr, nullptr, big, nullptr, nullptr);
  reduce8s_k<<<2048, 256, 0, stream>>>(hpbuf, big, outW, outW);  // model - data
  finalize_k<<<8, 256, 0, stream>>>(sums, out);
}

// Round 6
// 514.251 us; speedup vs baseline: 1.0790x; 1.0236x over previous
//
#include <hip/hip_runtime.h>

// RBM CD-1 step on MI355X — round 14.
// = round-13 kernel (verified 526.4us, equal-best) + two safe deltas:
//  (1) G2 (MODE 2) reads v as bf16-hi from v_cat (u16, 16MB tile traffic)
//      instead of f32 v (64MB). v_cat still live at G2 time (G3 overwrites
//      later). recon mean shifts ~5e-4 — noise vs sampling-flip absmax 4.0.
//      MODE-2 pf probe retargets to the u16 tile (2 chunks = 1024 L2 lines).
//  (2) prep_vt + prep_w merged into one flat-grid launch (4608 blocks):
//      one less boundary; w-prep traffic overlaps v-prep stream.
// Main GEMM loop, MODE-3 swizzle, all other epilogues: byte-identical to r13.

typedef unsigned short u16;
typedef short s16x8 __attribute__((ext_vector_type(8)));
typedef float f32x4 __attribute__((ext_vector_type(4)));
typedef u16 u16x4 __attribute__((ext_vector_type(4)));
typedef u16 u16x8 __attribute__((ext_vector_type(8)));

constexpr int Bn = 8192, Vn = 2048, Hn = 1024;
constexpr size_t VH = (size_t)Vn * Hn;
constexpr size_t BH = (size_t)Bn * Hn;
constexpr size_t OUT_RECON = BH;                        // 8388608
constexpr size_t OUT_WGRAD = OUT_RECON + 1;             // 8388609
constexpr size_t OUT_VBG   = OUT_WGRAD + VH;            // 10485761
constexpr size_t OUT_HBG   = OUT_VBG + Vn;              // 10487809

__device__ __forceinline__ u16 f2bf(float x) {
  union { float f; unsigned u; } a; a.f = x;
  unsigned r = a.u + 0x7FFFu + ((a.u >> 16) & 1u);   // RNE
  return (u16)(r >> 16);
}
__device__ __forceinline__ float bf2f(u16 h) {
  union { unsigned u; float f; } a; a.u = ((unsigned)h) << 16;
  return a.f;
}
__device__ __forceinline__ float sigmoidf_(float x) {
  return 1.0f / (1.0f + __expf(-x));
}

using gptr_t = const unsigned int __attribute__((address_space(1)))*;
using lptr_t = unsigned int __attribute__((address_space(3)))*;

__device__ __forceinline__ void gload16(const u16* g, u16* l) {
  __builtin_amdgcn_global_load_lds((gptr_t)(unsigned long long)g,
                                   (lptr_t)(unsigned long long)l, 16, 0, 0);
}

// ---------------- merged prep kernel ----------------
// blocks [0,4096): v[B,V] f32 -> v_cat[B,2V]=[hi|lo], vT[V,B], vbd partials.
// blocks [4096,4608): w[V,H] f32 -> w_cat[V,2H], wT_cat[H,2V].
__global__ void prep_all_k(const float* __restrict__ v, u16* __restrict__ vcat,
                           u16* __restrict__ vT, float* __restrict__ vbd_p,
                           const float* __restrict__ w, u16* __restrict__ w_cat,
                           u16* __restrict__ wTc) {
  __shared__ u16 tile16[64][68];
  __shared__ float cs[16][64];
  __shared__ float tile32[64][65];
  const int bx = blockIdx.x;
  const int t = threadIdx.x;
  if (bx < 4096) {
    const int b0 = (bx & 127) << 6, c0 = (bx >> 7) << 6;
    const int rg = t >> 4;          // 0..15 row group
    const int cg = (t & 15) << 2;   // col *4
    float ca[4] = {0.f, 0.f, 0.f, 0.f};
#pragma unroll
    for (int i = 0; i < 4; ++i) {
      int r = rg + 16 * i;
      f32x4 x = *(const f32x4*)&v[(size_t)(b0 + r) * Vn + c0 + cg];
      u16x4 hi, lo;
#pragma unroll
      for (int j = 0; j < 4; ++j) {
        hi[j] = f2bf(x[j]);
        lo[j] = f2bf(x[j] - bf2f(hi[j]));
        tile16[r][cg + j] = hi[j];
        ca[j] += x[j];
      }
      *(u16x4*)&vcat[(size_t)(b0 + r) * (2 * Vn) + c0 + cg] = hi;
      *(u16x4*)&vcat[(size_t)(b0 + r) * (2 * Vn) + Vn + c0 + cg] = lo;
    }
#pragma unroll
    for (int j = 0; j < 4; ++j) cs[rg][cg + j] = ca[j];
    __syncthreads();
    if (t < 64) {
      float s = 0.f;
#pragma unroll
      for (int k = 0; k < 16; ++k) s += cs[k][t];
      vbd_p[(size_t)(bx & 127) * Vn + c0 + t] = s;   // [128][2048]
    }
#pragma unroll
    for (int s2 = 0; s2 < 2; ++s2) {
      int c = t >> 2;
      int seg = (t & 3) + 4 * s2;
      u16x8 pk;
#pragma unroll
      for (int i = 0; i < 8; ++i) pk[i] = tile16[seg * 8 + i][c];
      *(u16x8*)&vT[(size_t)(c0 + c) * Bn + b0 + seg * 8] = pk;
    }
  } else {
    const int wb = bx - 4096;
    const int v0 = (wb & 31) << 6, h0 = (wb >> 5) << 6;
    const int c = t & 63, r = t >> 6;
    for (int rr = r; rr < 64; rr += 4) {
      float x = w[(size_t)(v0 + rr) * Hn + h0 + c];
      tile32[rr][c] = x;
      u16 hi = f2bf(x), lo = f2bf(x - bf2f(hi));
      w_cat[(size_t)(v0 + rr) * (2 * Hn) + h0 + c]      = hi;
      w_cat[(size_t)(v0 + rr) * (2 * Hn) + Hn + h0 + c] = lo;
    }
    __syncthreads();
    for (int rr = r; rr < 64; rr += 4) {
      float x = tile32[c][rr];  // = w[v0+c][h0+rr]
      u16 hi = f2bf(x), lo = f2bf(x - bf2f(hi));
      size_t ro = (size_t)(h0 + rr) * (2 * Vn);
      wTc[ro + v0 + c]      = hi;
      wTc[ro + Vn + v0 + c] = lo;
    }
  }
}

// ---- sampling epilogue for split-K [B,H] pre-activations ----------------
template <int M>
__global__ void epi_h_k(const float* __restrict__ p0, const float* __restrict__ p1,
                        const float* __restrict__ bias, const float* __restrict__ uni,
                        float* __restrict__ f32out, u16* __restrict__ hp_out,
                        u16* __restrict__ hbin_out, u16* __restrict__ tout,
                        float* __restrict__ colp) {
  __shared__ u16 tile[64][68];
  __shared__ float cs[16][64];
  const int b0 = blockIdx.x * 64, c0 = blockIdx.y * 64;
  const int t = threadIdx.x;
  const int rg = t >> 4, cg = (t & 15) << 2;
  float ca[4] = {0.f, 0.f, 0.f, 0.f};
#pragma unroll
  for (int i = 0; i < 4; ++i) {
    int r = rg + 16 * i;
    size_t e = (size_t)(b0 + r) * Hn + c0 + cg;
    f32x4 a = *(const f32x4*)&p0[e];
    f32x4 b = *(const f32x4*)&p1[e];
    f32x4 uu = *(const f32x4*)&uni[e];
    f32x4 hpv;
    u16x4 hb16, qv;
#pragma unroll
    for (int j = 0; j < 4; ++j) {
      float hp = sigmoidf_(a[j] + b[j] + bias[c0 + cg + j]);
      u16 qb = (hp > uu[j]) ? (u16)0x3F80 : (u16)0;
      tile[r][cg + j] = qb;
      if constexpr (M == 1) {
        hpv[j] = hp; hb16[j] = f2bf(hp); qv[j] = qb;
        ca[j] += hp;
      } else {
        ca[j] += (qb ? 1.f : 0.f);
      }
    }
    if constexpr (M == 1) {
      *(f32x4*)&f32out[e] = hpv;        // h_prediction (overwrites p0 region)
      *(u16x4*)&hp_out[e] = hb16;
      *(u16x4*)&hbin_out[e] = qv;
    }
  }
#pragma unroll
  for (int j = 0; j < 4; ++j) cs[rg][cg + j] = ca[j];
  __syncthreads();
  if (t < 64) {
    float s = 0.f;
#pragma unroll
    for (int k = 0; k < 16; ++k) s += cs[k][t];
    colp[(size_t)blockIdx.x * Hn + c0 + t] = s;   // [128][1024]
  }
#pragma unroll
  for (int s2 = 0; s2 < 2; ++s2) {
    int c = t >> 2;
    int seg = (t & 3) + 4 * s2;
    u16x8 pk;
#pragma unroll
    for (int i = 0; i < 8; ++i) pk[i] = tile[seg * 8 + i][c];
    *(u16x8*)&tout[(size_t)(c0 + c) * Bn + b0 + seg * 8] = pk;
  }
}

// ---------------- GEMM 256x256, BK=32, 8 waves, depth-4 counted pipeline --
// MODE 1: G1 split-K x2 partial (A remap [hi|hi|lo], B remap [hi|lo|hi]).
// MODE 2: G2 recon: A=h_p, B=w_cat hi, K=1024 -> recon partials; aux16=v_cat hi.
// MODE 3: split-K x8 grad: A,B += z*K cols -> (z<4?f32out:redp)+(z&3)*VH.
// MODE 4: G4 vk: A=hbin (dup), B=w_cat, K=2048 -> vk, vkT, vbm (fused).
// MODE 5: G5 split-K x2 partial: A=vk (dup), B=wT_cat.
template <int MODE>
__global__ __launch_bounds__(512) void gemm256(
    const u16* __restrict__ A, int lda, const u16* __restrict__ Bm, int ldb, int K,
    const float* __restrict__ bias, const float* __restrict__ uni,
    const float* __restrict__ aux, float* __restrict__ f32out,
    u16* __restrict__ bfout, const u16* __restrict__ aux16,
    float* __restrict__ redp, u16* __restrict__ tout, float* __restrict__ colp) {
  constexpr bool TRANS = (MODE == 4);
  constexpr bool PF = (MODE == 2 || MODE == 4);
  // As[4][256][32] at 0 (32768 u16), Bs[4][256][32] at 32768; 128 KB.
  // MODE4 epilogue ebuf [256][264] (67584 u16 = 132 KB) aliases everything.
  __shared__ __align__(16) u16 smem[TRANS ? 67584 : 65536];
  const int t = threadIdx.x;
  const int lane = t & 63, wave = t >> 6;                // 8 waves
  const int wr = (wave >> 2) << 7;                       // 0 / 128
  const int wc = (wave & 3) << 6;                        // 0/64/128/192
  // MODE-3-only XCD swizzle: grid (8,4,8), z = K-slice. HW: XCD = linear%8
  // (confirmed r12). Remap so XCD k owns z-slice k's full 8x4 MxN grid.
  int bidx = blockIdx.x, bidy = blockIdx.y, bidz = blockIdx.z;
  if constexpr (MODE == 3) {
    const int orig = blockIdx.x + (blockIdx.y << 3) + (blockIdx.z << 5);
    bidz = orig & 7;
    const int r = orig >> 3;       // 0..31 rank within XCD
    bidx = r & 7;
    bidy = r >> 3;
  }
  const int bm = bidx << 8, bn = bidy << 8;
  int kbeg = 0;
  float* pout = f32out;
  if constexpr (MODE == 1 || MODE == 5) {
    kbeg = bidz * K;
    pout = (bidz == 0) ? f32out : redp;
  }
  if constexpr (MODE == 3) {
    size_t off = (size_t)bidz * (size_t)K;
    A += off;
    Bm += off;
    pout = ((bidz < 4) ? f32out : redp) + (size_t)(bidz & 3) * VH;
  }
  f32x4 acc[8][4] = {};
  // staging (one gload = 512 thr x 16B = 128 rows x 64B): LDS row sr = t>>2,
  // granule t&3; fetch SWIZZLED global granule (t&3) ^ ((row>>1)&3) [r5 T2].
  const int sr = t >> 2;
  const int sc = (((t & 3) ^ ((t >> 3) & 3)) << 3);
  const u16* Ag  = A  + (size_t)(bm + sr) * lda + sc;
  const u16* Ag2 = Ag + (size_t)128 * lda;
  const u16* Bg  = Bm + (size_t)(bn + sr) * ldb + sc;
  const u16* Bg2 = Bg + (size_t)128 * ldb;
  const int fr = lane & 15, fg = lane >> 4;
  const int ga = ((fg ^ ((fr >> 1) & 3)) << 3);          // swizzled read granule

  auto stage = [&](int kt) {
    const int k0 = kbeg + (kt << 5);
    int acol, bcol;
    if constexpr (MODE == 1) {
      acol = (k0 < 2048) ? k0 : k0 - 2048;               // [hi|hi|lo]
      bcol = (k0 < 4096) ? k0 : k0 - 4096;               // [hi|lo|hi]
    } else if constexpr (MODE == 4) { acol = k0 & 1023; bcol = k0; }
    else if constexpr (MODE == 5)   { acol = k0 & 2047; bcol = k0; }
    else                            { acol = k0;        bcol = k0; }
    const int pb = kt & 3;
    u16* ad = smem + pb * 8192 + wave * 512;             // wave-uniform base
    u16* bd = smem + 32768 + pb * 8192 + wave * 512;
    gload16(Ag + acol, ad);
    gload16(Ag2 + acol, ad + 4096);
    gload16(Bg + bcol, bd);
    gload16(Bg2 + bcol, bd + 4096);
  };
  auto compute = [&](int kt) {
    const int pb = kt & 3;
    const u16* Ab = smem + pb * 8192;
    const u16* Bb = smem + 32768 + pb * 8192;
    s16x8 bf[4], af[4];
#pragma unroll
    for (int n = 0; n < 4; ++n)
      bf[n] = *(const s16x8*)&Bb[(wc + n * 16 + fr) * 32 + ga];
#pragma unroll
    for (int m = 0; m < 4; ++m)
      af[m] = *(const s16x8*)&Ab[(wr + m * 16 + fr) * 32 + ga];
    __builtin_amdgcn_s_setprio(1);
#pragma unroll
    for (int m = 0; m < 4; ++m)
#pragma unroll
      for (int n = 0; n < 4; ++n)
        acc[m][n] = __builtin_amdgcn_mfma_f32_16x16x32_bf16(af[m], bf[n], acc[m][n], 0, 0, 0);
    __builtin_amdgcn_s_setprio(0);
#pragma unroll
    for (int m = 0; m < 4; ++m)
      af[m] = *(const s16x8*)&Ab[(wr + (m + 4) * 16 + fr) * 32 + ga];
    __builtin_amdgcn_s_setprio(1);
#pragma unroll
    for (int m = 0; m < 4; ++m)
#pragma unroll
      for (int n = 0; n < 4; ++n)
        acc[m + 4][n] = __builtin_amdgcn_mfma_f32_16x16x32_bf16(af[m], bf[n], acc[m + 4][n], 0, 0, 0);
    __builtin_amdgcn_s_setprio(0);
  };
  // epilogue-tile L2 prefetch, one probe per 128B L2 line.
  // MODE 4: uni f32 [256][256] tile = 2048 lines = 4 chunks x 512 thr.
  // MODE 2: aux16 u16 tile (stride 4096) = 1024 lines = 2 chunks x 512 thr.
  auto pfl4 = [&](int ci) -> float {
    const int L = (ci << 9) + t;         // 0..2047
    return uni[(size_t)(bm + (L >> 3)) * Vn + bn + ((L & 7) << 5)];
  };
  auto pfl2 = [&](int ci) -> unsigned {
    const int L = (ci << 9) + t;         // 0..1023
    return (unsigned)aux16[(size_t)(bm + (L >> 2)) * 4096 + bn + ((L & 3) << 6)];
  };

  // depth-4 pipeline: stage T+3 each iter; vmcnt(8) waits own tile-T loads
  // (12 outstanding -> 8); barrier publishes all waves' slices.
  const int NT = K >> 5;               // >= 32 for all modes
  const int pfbeg = NT - 8;            // probes at T in [NT-8, ...)
  stage(0); stage(1); stage(2);
  int T = 0;
  for (; T < NT - 3; ++T) {
    asm volatile("s_waitcnt vmcnt(8)" ::: "memory");
    __builtin_amdgcn_s_barrier();
    asm volatile("" ::: "memory");
    stage(T + 3);
    if constexpr (MODE == 4) {
      if (T >= pfbeg && T < pfbeg + 4) {
        float pfv = pfl4(T - pfbeg);
        asm volatile("" :: "v"(pfv));
      }
    } else if constexpr (MODE == 2) {
      if (T >= pfbeg && T < pfbeg + 2) {
        unsigned pfv = pfl2(T - pfbeg);
        asm volatile("" :: "v"(pfv));
      }
    }
    compute(T);
  }
  asm volatile("s_waitcnt vmcnt(8)" ::: "memory");
  __builtin_amdgcn_s_barrier();
  asm volatile("" ::: "memory");
  compute(T++);
  asm volatile("s_waitcnt vmcnt(4)" ::: "memory");
  __builtin_amdgcn_s_barrier();
  asm volatile("" ::: "memory");
  compute(T++);
  asm volatile("s_waitcnt vmcnt(0)" ::: "memory");
  __builtin_amdgcn_s_barrier();
  asm volatile("" ::: "memory");
  compute(T);

  // ---- epilogue ----
  constexpr int NC = (MODE == 2 || MODE == 4) ? Vn : Hn;
  const int fq = lane >> 4;

  if constexpr (MODE == 1 || MODE == 3 || MODE == 5) {
#pragma unroll
    for (int m = 0; m < 8; ++m)
#pragma unroll
      for (int n = 0; n < 4; ++n)
#pragma unroll
        for (int j = 0; j < 4; ++j) {
          int rl = wr + m * 16 + fq * 4 + j;
          int cl = wc + n * 16 + fr;
          pout[(size_t)(bm + rl) * NC + bn + cl] = acc[m][n][j];
        }
  }

  if constexpr (MODE == 2) {
    // two-phase pipelined recon vs v_cat-hi (u16, stride 4096): issue 8 chunk
    // loads -> sigmoid in place -> depth-8 rolling-window consume (&7 static).
    float bcol[4];
#pragma unroll
    for (int n = 0; n < 4; ++n) bcol[n] = bias[bn + wc + n * 16 + fr];
    const size_t ebase = (size_t)(bm + wr + fq * 4) * 4096 + (bn + wc + fr);
    float ax[8][4];
    auto ld4 = [&](int ci, float* dst) {
      size_t e0 = ebase + (size_t)((ci >> 2) << 4) * 4096 + ((ci & 3) << 4);
      dst[0] = bf2f(aux16[e0]);            dst[1] = bf2f(aux16[e0 + 4096]);
      dst[2] = bf2f(aux16[e0 + 2 * 4096]); dst[3] = bf2f(aux16[e0 + 3 * 4096]);
    };
#pragma unroll
    for (int ci = 0; ci < 8; ++ci) ld4(ci, ax[ci]);
#pragma unroll
    for (int m = 0; m < 8; ++m)
#pragma unroll
      for (int n = 0; n < 4; ++n)
#pragma unroll
        for (int j = 0; j < 4; ++j)
          acc[m][n][j] = sigmoidf_(acc[m][n][j] + bcol[n]);
    float lsum = 0.f;
#pragma unroll
    for (int ci = 0; ci < 32; ++ci) {
      const int m = ci >> 2, n = ci & 3;
#pragma unroll
      for (int j = 0; j < 4; ++j) lsum += fabsf(ax[ci & 7][j] - acc[m][n][j]);
      if (ci < 24) ld4(ci + 8, ax[ci & 7]);
    }
#pragma unroll
    for (int off = 32; off > 0; off >>= 1) lsum += __shfl_down(lsum, off);
    __syncthreads();
    float* redlds = (float*)smem;
    if (lane == 0) redlds[wave] = lsum;
    __syncthreads();
    if (t == 0) {
      float s = 0.f;
#pragma unroll
      for (int wv = 0; wv < 8; ++wv) s += redlds[wv];
      redp[(size_t)blockIdx.y * gridDim.x + blockIdx.x] = s;
    }
  }

  if constexpr (MODE == 4) {
    __syncthreads();   // all waves done with dbuf before ebuf writes
    float bcol[4];
#pragma unroll
    for (int n = 0; n < 4; ++n) bcol[n] = bias[bn + wc + n * 16 + fr];
    const size_t ebase = (size_t)(bm + wr + fq * 4) * NC + (bn + wc + fr);
    float ux[8][4];
    auto ld4 = [&](int ci, float* dst) {
      size_t e0 = ebase + (size_t)((ci >> 2) << 4) * NC + ((ci & 3) << 4);
      dst[0] = uni[e0];          dst[1] = uni[e0 + NC];
      dst[2] = uni[e0 + 2 * NC]; dst[3] = uni[e0 + 3 * NC];
    };
#pragma unroll
    for (int ci = 0; ci < 8; ++ci) ld4(ci, ux[ci]);
#pragma unroll
    for (int m = 0; m < 8; ++m)
#pragma unroll
      for (int n = 0; n < 4; ++n)
#pragma unroll
        for (int j = 0; j < 4; ++j)
          acc[m][n][j] = sigmoidf_(acc[m][n][j] + bcol[n]);
    float csum[4] = {0.f, 0.f, 0.f, 0.f};
#pragma unroll
    for (int ci = 0; ci < 32; ++ci) {
      const int m = ci >> 2, n = ci & 3;
      const int rl = wr + m * 16 + fq * 4;
      const int cl = wc + n * 16 + fr;
#pragma unroll
      for (int j = 0; j < 4; ++j) {
        u16 qb = (acc[m][n][j] > ux[ci & 7][j]) ? (u16)0x3F80 : (u16)0;
        smem[(rl + j) * 264 + cl] = qb;          // ebuf (feeds vk AND vkT)
        csum[n] += (qb ? 1.f : 0.f);
      }
      if (ci < 24) ld4(ci + 8, ux[ci & 7]);
    }
    // vbm partials: lane covers 32 rows; xor16+xor32 reduces fq -> 128 rows
#pragma unroll
    for (int n = 0; n < 4; ++n) {
      float s = csum[n];
      s += __shfl_xor(s, 16);
      s += __shfl_xor(s, 32);
      if (fq == 0)
        colp[(size_t)(blockIdx.x * 2 + (wr >> 7)) * NC + (bn + wc + n * 16 + fr)] = s;
    }
    __syncthreads();   // ebuf fully written
    // vk row-major writeout: coalesced u16x8 from ebuf. 256 rows x 32
    // col-chunks = 8192 tasks / 512 thr; consecutive threads fill one row.
#pragma unroll
    for (int it = 0; it < 16; ++it) {
      int id = t + (it << 9);
      int r = id >> 5;                   // 0..255
      int c0 = (id & 31) << 3;           // 0..248
      u16x8 pk = *(const u16x8*)&smem[r * 264 + c0];
      *(u16x8*)&bfout[(size_t)(bm + r) * NC + bn + c0] = pk;
    }
    // transposed write-out: 256 cols x 32 row-groups(8) = 8192 tasks / 512 thr
#pragma unroll
    for (int it = 0; it < 16; ++it) {
      int id = t + (it << 9);
      int c = id & 255;
      int rg2 = id >> 8;                 // 0..31
      u16x8 pk;
#pragma unroll
      for (int i2 = 0; i2 < 8; ++i2) pk[i2] = smem[(rg2 * 8 + i2) * 264 + c];
      *(u16x8*)&tout[(size_t)(bn + c) * Bn + bm + rg2 * 8] = pk;
    }
  }
}

// out[i] = sum_{z<8} p[z][i]  (scalar stores: out base misaligned)
__global__ void reduce8_k(const float* __restrict__ p, float* __restrict__ out) {
  size_t e = ((size_t)blockIdx.x * 256 + threadIdx.x) * 4;
  f32x4 r = {};
#pragma unroll
  for (int z = 0; z < 8; ++z) r += *(const f32x4*)&p[(size_t)z * VH + e];
  out[e + 0] = r[0]; out[e + 1] = r[1]; out[e + 2] = r[2]; out[e + 3] = r[3];
}

// out[i] = sum_{z<4} pa[z][i] + sum_{z<4} pb[z][i] - sub[i]   (w_grad final)
__global__ void reduce8s_k(const float* __restrict__ pa, const float* __restrict__ pb,
                           const float* __restrict__ sub, float* __restrict__ out) {
  size_t e = ((size_t)blockIdx.x * 256 + threadIdx.x) * 4;
  f32x4 r = {};
#pragma unroll
  for (int z = 0; z < 4; ++z) r += *(const f32x4*)&pa[(size_t)z * VH + e];
#pragma unroll
  for (int z = 0; z < 4; ++z) r += *(const f32x4*)&pb[(size_t)z * VH + e];
  float s0 = sub[e + 0], s1 = sub[e + 1], s2 = sub[e + 2], s3 = sub[e + 3];
  out[e + 0] = r[0] - s0; out[e + 1] = r[1] - s1;
  out[e + 2] = r[2] - s2; out[e + 3] = r[3] - s3;
}

// final reductions: bias grads + recon scalar
// vbd:128 part., hbd:128, vbm:64, hbm:128, recon:256
__global__ void finalize_k(const float* __restrict__ sums, float* __restrict__ out) {
  int i = blockIdx.x * 256 + threadIdx.x;
  const float* recon_p = sums;                 // 256
  const float* vbd = sums + 1024;              // 128 x 2048
  const float* hbd = vbd + 128 * 2048;         // 128 x 1024
  const float* vbm = hbd + 128 * 1024;         // 64 x 2048
  const float* hbm = vbm + 128 * 2048;         // 128 x 1024
  if (i < 2048) {
    float d = 0.f, m = 0.f;
    for (int k = 0; k < 128; ++k) d += vbd[k * 2048 + i];
    for (int k = 0; k < 64; ++k)  m += vbm[k * 2048 + i];
    out[OUT_VBG + i] = m - d;
  }
  if (i < 1024) {
    float d = 0.f, m = 0.f;
    for (int k = 0; k < 128; ++k) { d += hbd[k * 1024 + i]; m += hbm[k * 1024 + i]; }
    out[OUT_HBG + i] = m - d;
  }
  if (i == 0) {
    float s = 0.f;
    for (int k = 0; k < 256; ++k) s += recon_p[k];
    out[OUT_RECON] = s * (1.0f / 16777216.0f);  // /(B*V)
  }
}

extern "C" void kernel_launch(void* const* d_in, const int* in_sizes, int n_in,
                              void* d_out, int out_size, void* d_ws, size_t ws_size,
                              hipStream_t stream) {
  (void)in_sizes; (void)n_in; (void)out_size;
  const float* v   = (const float*)d_in[0];
  const float* w   = (const float*)d_in[1];
  const float* vb  = (const float*)d_in[2];
  const float* hb  = (const float*)d_in[3];
  const float* u_h = (const float*)d_in[4];
  const float* u_v = (const float*)d_in[5];
  float* out = (float*)d_out;
  char* ws = (char*)d_ws;
  if (ws_size < 204734464ULL) return;

  float* sums    = (float*)ws;               // 3.25 MiB region
  float* recon_p = sums;                     // 256
  float* vbd_p   = sums + 1024;              // 128*2048
  float* hbd_p   = vbd_p + 128 * 2048;       // 128*1024
  float* vbm_p   = hbd_p + 128 * 1024;       // 64*2048
  float* hbm_p   = vbm_p + 128 * 2048;       // 128*1024
  char* p = ws + 3407872;
  u16* v_cat  = (u16*)p;  p += (size_t)Bn * 2 * Vn * 2;   // 64 MiB [B,2V]
  u16* wT_cat = (u16*)p;  p += (size_t)Hn * 2 * Vn * 2;   // 8 MiB [H,2V]
  u16* w_cat  = (u16*)p;  p += (size_t)Vn * 2 * Hn * 2;   // 8 MiB [V,2H]
  u16* h_p    = (u16*)p;  p += BH * 2;                    // 16 MiB [B,H]
  u16* hbin   = (u16*)p;  p += BH * 2;                    // 16 MiB [B,H]
  u16* vT     = (u16*)p;  p += (size_t)Vn * Bn * 2;       // 32 MiB [V,B]
  u16* hT     = (u16*)p;  p += (size_t)Hn * Bn * 2;       // 16 MiB [H,B]
  float* big  = (float*)p;                                // 32 MiB time-shared
  u16* vk   = v_cat;            // v_cat dead after G2 (G3 partials overwrite)
  u16* vkT  = vT;               // vT dead after G3
  u16* h2T  = hT;               // hT dead after G3
  float* vcat_f = (float*)v_cat;   // 64 MiB: G3's 8 partials
  float* hpbuf  = (float*)h_p;     // h_p+hbin region (32 MiB) as f32 partials
  float* outW   = out + OUT_WGRAD;

  prep_all_k<<<4608, 256, 0, stream>>>(v, v_cat, vT, vbd_p, w, w_cat, wT_cat);
  // G1a: split-K x2 partials (z0 -> out[0..BH) scratch, z1 -> big)
  gemm256<1><<<dim3(32, 4, 2), 512, 0, stream>>>(
      v_cat, 2 * Vn, wT_cat, 2 * Vn, 3072, nullptr, nullptr, nullptr,
      out, nullptr, nullptr, big, nullptr, nullptr);
  // epi: h_pred / h_p / hbin / hT / hbd
  epi_h_k<1><<<dim3(128, 16), 256, 0, stream>>>(
      out, big, hb, u_h, out, h_p, hbin, hT, hbd_p);
  // G2: recon partials (256 blocks); aux16 = v_cat hi (still live)
  gemm256<2><<<dim3(32, 8), 512, 0, stream>>>(
      h_p, Hn, w_cat, 2 * Hn, Hn, vb, nullptr, nullptr,
      nullptr, nullptr, v_cat, recon_p, nullptr, nullptr);
  // G3: w_data_grad partials (split-K x8 -> v_cat region, 64 MiB)
  gemm256<3><<<dim3(Vn / 256, Hn / 256, 8), 512, 0, stream>>>(
      vT, Bn, hT, Bn, 1024, nullptr, nullptr, nullptr,
      vcat_f, nullptr, nullptr, vcat_f + 4 * VH, nullptr, nullptr);
  reduce8_k<<<2048, 256, 0, stream>>>(vcat_f, outW);   // outW = data-grad sum
  // G4: vk/vkT + vbm partials (fused sample+transpose epilogue)
  gemm256<4><<<dim3(32, 8), 512, 0, stream>>>(
      hbin, Hn, w_cat, 2 * Hn, 2 * Hn, vb, u_v, nullptr,
      nullptr, vk, nullptr, nullptr, vkT, vbm_p);
  // G5a: split-K x2 partials (z0 -> hpbuf, z1 -> big); h_p/hbin dead now
  gemm256<5><<<dim3(32, 4, 2), 512, 0, stream>>>(
      vk, Vn, wT_cat, 2 * Vn, 2048, nullptr, nullptr, nullptr,
      hpbuf, nullptr, nullptr, big, nullptr, nullptr);
  // epi: h2T + hbm
  epi_h_k<5><<<dim3(128, 16), 256, 0, stream>>>(
      hpbuf, big, hb, u_h + BH, nullptr, nullptr, nullptr, h2T, hbm_p);
  // G6: w_model_grad partials (split-K x8: z<4 -> hpbuf, z>=4 -> big)
  gemm256<3><<<dim3(Vn / 256, Hn / 256, 8), 512, 0, stream>>>(
      vkT, Bn, h2T, Bn, 1024, nullptr, nullptr, nullptr,
      hpbuf, nullptr, nullptr, big, nullptr, nullptr);
  reduce8s_k<<<2048, 256, 0, stream>>>(hpbuf, big, outW, outW);  // model - data
  finalize_k<<<8, 256, 0, stream>>>(sums, out);
}

// Round 7
// 503.039 us; speedup vs baseline: 1.1031x; 1.0223x over previous
//
#include <hip/hip_runtime.h>

// RBM CD-1 step on MI355X — round 15.
// = round-14 kernel (verified 514.3us, best) + ONE delta: MODE-4 vkT
// transposed writeout goes 64B-contiguous-per-thread (4x u16x8 to one 64B
// line; r10's variant, this time isolated). r14's loop had each wave store
// touching 64 lines x 16B (4x write amplification on vkT = the +36MB WRITE
// excess measured: 101MB vs 65MB ideal). LDS-read side unchanged
// (conflict-free either way). Everything else byte-identical to r14.

typedef unsigned short u16;
typedef short s16x8 __attribute__((ext_vector_type(8)));
typedef float f32x4 __attribute__((ext_vector_type(4)));
typedef u16 u16x4 __attribute__((ext_vector_type(4)));
typedef u16 u16x8 __attribute__((ext_vector_type(8)));

constexpr int Bn = 8192, Vn = 2048, Hn = 1024;
constexpr size_t VH = (size_t)Vn * Hn;
constexpr size_t BH = (size_t)Bn * Hn;
constexpr size_t OUT_RECON = BH;                        // 8388608
constexpr size_t OUT_WGRAD = OUT_RECON + 1;             // 8388609
constexpr size_t OUT_VBG   = OUT_WGRAD + VH;            // 10485761
constexpr size_t OUT_HBG   = OUT_VBG + Vn;              // 10487809

__device__ __forceinline__ u16 f2bf(float x) {
  union { float f; unsigned u; } a; a.f = x;
  unsigned r = a.u + 0x7FFFu + ((a.u >> 16) & 1u);   // RNE
  return (u16)(r >> 16);
}
__device__ __forceinline__ float bf2f(u16 h) {
  union { unsigned u; float f; } a; a.u = ((unsigned)h) << 16;
  return a.f;
}
__device__ __forceinline__ float sigmoidf_(float x) {
  return 1.0f / (1.0f + __expf(-x));
}

using gptr_t = const unsigned int __attribute__((address_space(1)))*;
using lptr_t = unsigned int __attribute__((address_space(3)))*;

__device__ __forceinline__ void gload16(const u16* g, u16* l) {
  __builtin_amdgcn_global_load_lds((gptr_t)(unsigned long long)g,
                                   (lptr_t)(unsigned long long)l, 16, 0, 0);
}

// ---------------- merged prep kernel ----------------
// blocks [0,4096): v[B,V] f32 -> v_cat[B,2V]=[hi|lo], vT[V,B], vbd partials.
// blocks [4096,4608): w[V,H] f32 -> w_cat[V,2H], wT_cat[H,2V].
__global__ void prep_all_k(const float* __restrict__ v, u16* __restrict__ vcat,
                           u16* __restrict__ vT, float* __restrict__ vbd_p,
                           const float* __restrict__ w, u16* __restrict__ w_cat,
                           u16* __restrict__ wTc) {
  __shared__ u16 tile16[64][68];
  __shared__ float cs[16][64];
  __shared__ float tile32[64][65];
  const int bx = blockIdx.x;
  const int t = threadIdx.x;
  if (bx < 4096) {
    const int b0 = (bx & 127) << 6, c0 = (bx >> 7) << 6;
    const int rg = t >> 4;          // 0..15 row group
    const int cg = (t & 15) << 2;   // col *4
    float ca[4] = {0.f, 0.f, 0.f, 0.f};
#pragma unroll
    for (int i = 0; i < 4; ++i) {
      int r = rg + 16 * i;
      f32x4 x = *(const f32x4*)&v[(size_t)(b0 + r) * Vn + c0 + cg];
      u16x4 hi, lo;
#pragma unroll
      for (int j = 0; j < 4; ++j) {
        hi[j] = f2bf(x[j]);
        lo[j] = f2bf(x[j] - bf2f(hi[j]));
        tile16[r][cg + j] = hi[j];
        ca[j] += x[j];
      }
      *(u16x4*)&vcat[(size_t)(b0 + r) * (2 * Vn) + c0 + cg] = hi;
      *(u16x4*)&vcat[(size_t)(b0 + r) * (2 * Vn) + Vn + c0 + cg] = lo;
    }
#pragma unroll
    for (int j = 0; j < 4; ++j) cs[rg][cg + j] = ca[j];
    __syncthreads();
    if (t < 64) {
      float s = 0.f;
#pragma unroll
      for (int k = 0; k < 16; ++k) s += cs[k][t];
      vbd_p[(size_t)(bx & 127) * Vn + c0 + t] = s;   // [128][2048]
    }
#pragma unroll
    for (int s2 = 0; s2 < 2; ++s2) {
      int c = t >> 2;
      int seg = (t & 3) + 4 * s2;
      u16x8 pk;
#pragma unroll
      for (int i = 0; i < 8; ++i) pk[i] = tile16[seg * 8 + i][c];
      *(u16x8*)&vT[(size_t)(c0 + c) * Bn + b0 + seg * 8] = pk;
    }
  } else {
    const int wb = bx - 4096;
    const int v0 = (wb & 31) << 6, h0 = (wb >> 5) << 6;
    const int c = t & 63, r = t >> 6;
    for (int rr = r; rr < 64; rr += 4) {
      float x = w[(size_t)(v0 + rr) * Hn + h0 + c];
      tile32[rr][c] = x;
      u16 hi = f2bf(x), lo = f2bf(x - bf2f(hi));
      w_cat[(size_t)(v0 + rr) * (2 * Hn) + h0 + c]      = hi;
      w_cat[(size_t)(v0 + rr) * (2 * Hn) + Hn + h0 + c] = lo;
    }
    __syncthreads();
    for (int rr = r; rr < 64; rr += 4) {
      float x = tile32[c][rr];  // = w[v0+c][h0+rr]
      u16 hi = f2bf(x), lo = f2bf(x - bf2f(hi));
      size_t ro = (size_t)(h0 + rr) * (2 * Vn);
      wTc[ro + v0 + c]      = hi;
      wTc[ro + Vn + v0 + c] = lo;
    }
  }
}

// ---- sampling epilogue for split-K [B,H] pre-activations ----------------
template <int M>
__global__ void epi_h_k(const float* __restrict__ p0, const float* __restrict__ p1,
                        const float* __restrict__ bias, const float* __restrict__ uni,
                        float* __restrict__ f32out, u16* __restrict__ hp_out,
                        u16* __restrict__ hbin_out, u16* __restrict__ tout,
                        float* __restrict__ colp) {
  __shared__ u16 tile[64][68];
  __shared__ float cs[16][64];
  const int b0 = blockIdx.x * 64, c0 = blockIdx.y * 64;
  const int t = threadIdx.x;
  const int rg = t >> 4, cg = (t & 15) << 2;
  float ca[4] = {0.f, 0.f, 0.f, 0.f};
#pragma unroll
  for (int i = 0; i < 4; ++i) {
    int r = rg + 16 * i;
    size_t e = (size_t)(b0 + r) * Hn + c0 + cg;
    f32x4 a = *(const f32x4*)&p0[e];
    f32x4 b = *(const f32x4*)&p1[e];
    f32x4 uu = *(const f32x4*)&uni[e];
    f32x4 hpv;
    u16x4 hb16, qv;
#pragma unroll
    for (int j = 0; j < 4; ++j) {
      float hp = sigmoidf_(a[j] + b[j] + bias[c0 + cg + j]);
      u16 qb = (hp > uu[j]) ? (u16)0x3F80 : (u16)0;
      tile[r][cg + j] = qb;
      if constexpr (M == 1) {
        hpv[j] = hp; hb16[j] = f2bf(hp); qv[j] = qb;
        ca[j] += hp;
      } else {
        ca[j] += (qb ? 1.f : 0.f);
      }
    }
    if constexpr (M == 1) {
      *(f32x4*)&f32out[e] = hpv;        // h_prediction (overwrites p0 region)
      *(u16x4*)&hp_out[e] = hb16;
      *(u16x4*)&hbin_out[e] = qv;
    }
  }
#pragma unroll
  for (int j = 0; j < 4; ++j) cs[rg][cg + j] = ca[j];
  __syncthreads();
  if (t < 64) {
    float s = 0.f;
#pragma unroll
    for (int k = 0; k < 16; ++k) s += cs[k][t];
    colp[(size_t)blockIdx.x * Hn + c0 + t] = s;   // [128][1024]
  }
#pragma unroll
  for (int s2 = 0; s2 < 2; ++s2) {
    int c = t >> 2;
    int seg = (t & 3) + 4 * s2;
    u16x8 pk;
#pragma unroll
    for (int i = 0; i < 8; ++i) pk[i] = tile[seg * 8 + i][c];
    *(u16x8*)&tout[(size_t)(c0 + c) * Bn + b0 + seg * 8] = pk;
  }
}

// ---------------- GEMM 256x256, BK=32, 8 waves, depth-4 counted pipeline --
// MODE 1: G1 split-K x2 partial (A remap [hi|hi|lo], B remap [hi|lo|hi]).
// MODE 2: G2 recon: A=h_p, B=w_cat hi, K=1024 -> recon partials; aux16=v_cat hi.
// MODE 3: split-K x8 grad: A,B += z*K cols -> (z<4?f32out:redp)+(z&3)*VH.
// MODE 4: G4 vk: A=hbin (dup), B=w_cat, K=2048 -> vk, vkT, vbm (fused).
// MODE 5: G5 split-K x2 partial: A=vk (dup), B=wT_cat.
template <int MODE>
__global__ __launch_bounds__(512) void gemm256(
    const u16* __restrict__ A, int lda, const u16* __restrict__ Bm, int ldb, int K,
    const float* __restrict__ bias, const float* __restrict__ uni,
    const float* __restrict__ aux, float* __restrict__ f32out,
    u16* __restrict__ bfout, const u16* __restrict__ aux16,
    float* __restrict__ redp, u16* __restrict__ tout, float* __restrict__ colp) {
  constexpr bool TRANS = (MODE == 4);
  // As[4][256][32] at 0 (32768 u16), Bs[4][256][32] at 32768; 128 KB.
  // MODE4 epilogue ebuf [256][264] (67584 u16 = 132 KB) aliases everything.
  __shared__ __align__(16) u16 smem[TRANS ? 67584 : 65536];
  const int t = threadIdx.x;
  const int lane = t & 63, wave = t >> 6;                // 8 waves
  const int wr = (wave >> 2) << 7;                       // 0 / 128
  const int wc = (wave & 3) << 6;                        // 0/64/128/192
  // MODE-3-only XCD swizzle: grid (8,4,8), z = K-slice. HW: XCD = linear%8
  // (confirmed r12). Remap so XCD k owns z-slice k's full 8x4 MxN grid.
  int bidx = blockIdx.x, bidy = blockIdx.y, bidz = blockIdx.z;
  if constexpr (MODE == 3) {
    const int orig = blockIdx.x + (blockIdx.y << 3) + (blockIdx.z << 5);
    bidz = orig & 7;
    const int r = orig >> 3;       // 0..31 rank within XCD
    bidx = r & 7;
    bidy = r >> 3;
  }
  const int bm = bidx << 8, bn = bidy << 8;
  int kbeg = 0;
  float* pout = f32out;
  if constexpr (MODE == 1 || MODE == 5) {
    kbeg = bidz * K;
    pout = (bidz == 0) ? f32out : redp;
  }
  if constexpr (MODE == 3) {
    size_t off = (size_t)bidz * (size_t)K;
    A += off;
    Bm += off;
    pout = ((bidz < 4) ? f32out : redp) + (size_t)(bidz & 3) * VH;
  }
  f32x4 acc[8][4] = {};
  // staging (one gload = 512 thr x 16B = 128 rows x 64B): LDS row sr = t>>2,
  // granule t&3; fetch SWIZZLED global granule (t&3) ^ ((row>>1)&3) [r5 T2].
  const int sr = t >> 2;
  const int sc = (((t & 3) ^ ((t >> 3) & 3)) << 3);
  const u16* Ag  = A  + (size_t)(bm + sr) * lda + sc;
  const u16* Ag2 = Ag + (size_t)128 * lda;
  const u16* Bg  = Bm + (size_t)(bn + sr) * ldb + sc;
  const u16* Bg2 = Bg + (size_t)128 * ldb;
  const int fr = lane & 15, fg = lane >> 4;
  const int ga = ((fg ^ ((fr >> 1) & 3)) << 3);          // swizzled read granule

  auto stage = [&](int kt) {
    const int k0 = kbeg + (kt << 5);
    int acol, bcol;
    if constexpr (MODE == 1) {
      acol = (k0 < 2048) ? k0 : k0 - 2048;               // [hi|hi|lo]
      bcol = (k0 < 4096) ? k0 : k0 - 4096;               // [hi|lo|hi]
    } else if constexpr (MODE == 4) { acol = k0 & 1023; bcol = k0; }
    else if constexpr (MODE == 5)   { acol = k0 & 2047; bcol = k0; }
    else                            { acol = k0;        bcol = k0; }
    const int pb = kt & 3;
    u16* ad = smem + pb * 8192 + wave * 512;             // wave-uniform base
    u16* bd = smem + 32768 + pb * 8192 + wave * 512;
    gload16(Ag + acol, ad);
    gload16(Ag2 + acol, ad + 4096);
    gload16(Bg + bcol, bd);
    gload16(Bg2 + bcol, bd + 4096);
  };
  auto compute = [&](int kt) {
    const int pb = kt & 3;
    const u16* Ab = smem + pb * 8192;
    const u16* Bb = smem + 32768 + pb * 8192;
    s16x8 bf[4], af[4];
#pragma unroll
    for (int n = 0; n < 4; ++n)
      bf[n] = *(const s16x8*)&Bb[(wc + n * 16 + fr) * 32 + ga];
#pragma unroll
    for (int m = 0; m < 4; ++m)
      af[m] = *(const s16x8*)&Ab[(wr + m * 16 + fr) * 32 + ga];
    __builtin_amdgcn_s_setprio(1);
#pragma unroll
    for (int m = 0; m < 4; ++m)
#pragma unroll
      for (int n = 0; n < 4; ++n)
        acc[m][n] = __builtin_amdgcn_mfma_f32_16x16x32_bf16(af[m], bf[n], acc[m][n], 0, 0, 0);
    __builtin_amdgcn_s_setprio(0);
#pragma unroll
    for (int m = 0; m < 4; ++m)
      af[m] = *(const s16x8*)&Ab[(wr + (m + 4) * 16 + fr) * 32 + ga];
    __builtin_amdgcn_s_setprio(1);
#pragma unroll
    for (int m = 0; m < 4; ++m)
#pragma unroll
      for (int n = 0; n < 4; ++n)
        acc[m + 4][n] = __builtin_amdgcn_mfma_f32_16x16x32_bf16(af[m], bf[n], acc[m + 4][n], 0, 0, 0);
    __builtin_amdgcn_s_setprio(0);
  };
  // epilogue-tile L2 prefetch, one probe per 128B L2 line.
  // MODE 4: uni f32 [256][256] tile = 2048 lines = 4 chunks x 512 thr.
  // MODE 2: aux16 u16 tile (stride 4096) = 1024 lines = 2 chunks x 512 thr.
  auto pfl4 = [&](int ci) -> float {
    const int L = (ci << 9) + t;         // 0..2047
    return uni[(size_t)(bm + (L >> 3)) * Vn + bn + ((L & 7) << 5)];
  };
  auto pfl2 = [&](int ci) -> unsigned {
    const int L = (ci << 9) + t;         // 0..1023
    return (unsigned)aux16[(size_t)(bm + (L >> 2)) * 4096 + bn + ((L & 3) << 6)];
  };

  // depth-4 pipeline: stage T+3 each iter; vmcnt(8) waits own tile-T loads
  // (12 outstanding -> 8); barrier publishes all waves' slices.
  const int NT = K >> 5;               // >= 32 for all modes
  const int pfbeg = NT - 8;            // probes at T in [NT-8, ...)
  stage(0); stage(1); stage(2);
  int T = 0;
  for (; T < NT - 3; ++T) {
    asm volatile("s_waitcnt vmcnt(8)" ::: "memory");
    __builtin_amdgcn_s_barrier();
    asm volatile("" ::: "memory");
    stage(T + 3);
    if constexpr (MODE == 4) {
      if (T >= pfbeg && T < pfbeg + 4) {
        float pfv = pfl4(T - pfbeg);
        asm volatile("" :: "v"(pfv));
      }
    } else if constexpr (MODE == 2) {
      if (T >= pfbeg && T < pfbeg + 2) {
        unsigned pfv = pfl2(T - pfbeg);
        asm volatile("" :: "v"(pfv));
      }
    }
    compute(T);
  }
  asm volatile("s_waitcnt vmcnt(8)" ::: "memory");
  __builtin_amdgcn_s_barrier();
  asm volatile("" ::: "memory");
  compute(T++);
  asm volatile("s_waitcnt vmcnt(4)" ::: "memory");
  __builtin_amdgcn_s_barrier();
  asm volatile("" ::: "memory");
  compute(T++);
  asm volatile("s_waitcnt vmcnt(0)" ::: "memory");
  __builtin_amdgcn_s_barrier();
  asm volatile("" ::: "memory");
  compute(T);

  // ---- epilogue ----
  constexpr int NC = (MODE == 2 || MODE == 4) ? Vn : Hn;
  const int fq = lane >> 4;

  if constexpr (MODE == 1 || MODE == 3 || MODE == 5) {
#pragma unroll
    for (int m = 0; m < 8; ++m)
#pragma unroll
      for (int n = 0; n < 4; ++n)
#pragma unroll
        for (int j = 0; j < 4; ++j) {
          int rl = wr + m * 16 + fq * 4 + j;
          int cl = wc + n * 16 + fr;
          pout[(size_t)(bm + rl) * NC + bn + cl] = acc[m][n][j];
        }
  }

  if constexpr (MODE == 2) {
    // two-phase pipelined recon vs v_cat-hi (u16, stride 4096): issue 8 chunk
    // loads -> sigmoid in place -> depth-8 rolling-window consume (&7 static).
    float bcol[4];
#pragma unroll
    for (int n = 0; n < 4; ++n) bcol[n] = bias[bn + wc + n * 16 + fr];
    const size_t ebase = (size_t)(bm + wr + fq * 4) * 4096 + (bn + wc + fr);
    float ax[8][4];
    auto ld4 = [&](int ci, float* dst) {
      size_t e0 = ebase + (size_t)((ci >> 2) << 4) * 4096 + ((ci & 3) << 4);
      dst[0] = bf2f(aux16[e0]);            dst[1] = bf2f(aux16[e0 + 4096]);
      dst[2] = bf2f(aux16[e0 + 2 * 4096]); dst[3] = bf2f(aux16[e0 + 3 * 4096]);
    };
#pragma unroll
    for (int ci = 0; ci < 8; ++ci) ld4(ci, ax[ci]);
#pragma unroll
    for (int m = 0; m < 8; ++m)
#pragma unroll
      for (int n = 0; n < 4; ++n)
#pragma unroll
        for (int j = 0; j < 4; ++j)
          acc[m][n][j] = sigmoidf_(acc[m][n][j] + bcol[n]);
    float lsum = 0.f;
#pragma unroll
    for (int ci = 0; ci < 32; ++ci) {
      const int m = ci >> 2, n = ci & 3;
#pragma unroll
      for (int j = 0; j < 4; ++j) lsum += fabsf(ax[ci & 7][j] - acc[m][n][j]);
      if (ci < 24) ld4(ci + 8, ax[ci & 7]);
    }
#pragma unroll
    for (int off = 32; off > 0; off >>= 1) lsum += __shfl_down(lsum, off);
    __syncthreads();
    float* redlds = (float*)smem;
    if (lane == 0) redlds[wave] = lsum;
    __syncthreads();
    if (t == 0) {
      float s = 0.f;
#pragma unroll
      for (int wv = 0; wv < 8; ++wv) s += redlds[wv];
      redp[(size_t)blockIdx.y * gridDim.x + blockIdx.x] = s;
    }
  }

  if constexpr (MODE == 4) {
    __syncthreads();   // all waves done with dbuf before ebuf writes
    float bcol[4];
#pragma unroll
    for (int n = 0; n < 4; ++n) bcol[n] = bias[bn + wc + n * 16 + fr];
    const size_t ebase = (size_t)(bm + wr + fq * 4) * NC + (bn + wc + fr);
    float ux[8][4];
    auto ld4 = [&](int ci, float* dst) {
      size_t e0 = ebase + (size_t)((ci >> 2) << 4) * NC + ((ci & 3) << 4);
      dst[0] = uni[e0];          dst[1] = uni[e0 + NC];
      dst[2] = uni[e0 + 2 * NC]; dst[3] = uni[e0 + 3 * NC];
    };
#pragma unroll
    for (int ci = 0; ci < 8; ++ci) ld4(ci, ux[ci]);
#pragma unroll
    for (int m = 0; m < 8; ++m)
#pragma unroll
      for (int n = 0; n < 4; ++n)
#pragma unroll
        for (int j = 0; j < 4; ++j)
          acc[m][n][j] = sigmoidf_(acc[m][n][j] + bcol[n]);
    float csum[4] = {0.f, 0.f, 0.f, 0.f};
#pragma unroll
    for (int ci = 0; ci < 32; ++ci) {
      const int m = ci >> 2, n = ci & 3;
      const int rl = wr + m * 16 + fq * 4;
      const int cl = wc + n * 16 + fr;
#pragma unroll
      for (int j = 0; j < 4; ++j) {
        u16 qb = (acc[m][n][j] > ux[ci & 7][j]) ? (u16)0x3F80 : (u16)0;
        smem[(rl + j) * 264 + cl] = qb;          // ebuf (feeds vk AND vkT)
        csum[n] += (qb ? 1.f : 0.f);
      }
      if (ci < 24) ld4(ci + 8, ux[ci & 7]);
    }
    // vbm partials: lane covers 32 rows; xor16+xor32 reduces fq -> 128 rows
#pragma unroll
    for (int n = 0; n < 4; ++n) {
      float s = csum[n];
      s += __shfl_xor(s, 16);
      s += __shfl_xor(s, 32);
      if (fq == 0)
        colp[(size_t)(blockIdx.x * 2 + (wr >> 7)) * NC + (bn + wc + n * 16 + fr)] = s;
    }
    __syncthreads();   // ebuf fully written
    // vk row-major writeout: coalesced u16x8 from ebuf. 256 rows x 32
    // col-chunks = 8192 tasks / 512 thr; consecutive threads fill one row.
#pragma unroll
    for (int it = 0; it < 16; ++it) {
      int id = t + (it << 9);
      int r = id >> 5;                   // 0..255
      int c0 = (id & 31) << 3;           // 0..248
      u16x8 pk = *(const u16x8*)&smem[r * 264 + c0];
      *(u16x8*)&bfout[(size_t)(bm + r) * NC + bn + c0] = pk;
    }
    // transposed write-out, 64B-contiguous per thread: thread owns
    // (col c, 32-row span q*32); 4x u16x8 stores land in ONE 64B line.
#pragma unroll
    for (int it = 0; it < 4; ++it) {
      int id = t + (it << 9);
      int c = id & 255;
      int q = id >> 8;                   // 0..7
#pragma unroll
      for (int i8 = 0; i8 < 4; ++i8) {
        u16x8 pk;
#pragma unroll
        for (int i2 = 0; i2 < 8; ++i2)
          pk[i2] = smem[(q * 32 + i8 * 8 + i2) * 264 + c];
        *(u16x8*)&tout[(size_t)(bn + c) * Bn + bm + q * 32 + i8 * 8] = pk;
      }
    }
  }
}

// out[i] = sum_{z<8} p[z][i]  (scalar stores: out base misaligned)
__global__ void reduce8_k(const float* __restrict__ p, float* __restrict__ out) {
  size_t e = ((size_t)blockIdx.x * 256 + threadIdx.x) * 4;
  f32x4 r = {};
#pragma unroll
  for (int z = 0; z < 8; ++z) r += *(const f32x4*)&p[(size_t)z * VH + e];
  out[e + 0] = r[0]; out[e + 1] = r[1]; out[e + 2] = r[2]; out[e + 3] = r[3];
}

// out[i] = sum_{z<4} pa[z][i] + sum_{z<4} pb[z][i] - sub[i]   (w_grad final)
__global__ void reduce8s_k(const float* __restrict__ pa, const float* __restrict__ pb,
                           const float* __restrict__ sub, float* __restrict__ out) {
  size_t e = ((size_t)blockIdx.x * 256 + threadIdx.x) * 4;
  f32x4 r = {};
#pragma unroll
  for (int z = 0; z < 4; ++z) r += *(const f32x4*)&pa[(size_t)z * VH + e];
#pragma unroll
  for (int z = 0; z < 4; ++z) r += *(const f32x4*)&pb[(size_t)z * VH + e];
  float s0 = sub[e + 0], s1 = sub[e + 1], s2 = sub[e + 2], s3 = sub[e + 3];
  out[e + 0] = r[0] - s0; out[e + 1] = r[1] - s1;
  out[e + 2] = r[2] - s2; out[e + 3] = r[3] - s3;
}

// final reductions: bias grads + recon scalar
// vbd:128 part., hbd:128, vbm:64, hbm:128, recon:256
__global__ void finalize_k(const float* __restrict__ sums, float* __restrict__ out) {
  int i = blockIdx.x * 256 + threadIdx.x;
  const float* recon_p = sums;                 // 256
  const float* vbd = sums + 1024;              // 128 x 2048
  const float* hbd = vbd + 128 * 2048;         // 128 x 1024
  const float* vbm = hbd + 128 * 1024;         // 64 x 2048
  const float* hbm = vbm + 128 * 2048;         // 128 x 1024
  if (i < 2048) {
    float d = 0.f, m = 0.f;
    for (int k = 0; k < 128; ++k) d += vbd[k * 2048 + i];
    for (int k = 0; k < 64; ++k)  m += vbm[k * 2048 + i];
    out[OUT_VBG + i] = m - d;
  }
  if (i < 1024) {
    float d = 0.f, m = 0.f;
    for (int k = 0; k < 128; ++k) { d += hbd[k * 1024 + i]; m += hbm[k * 1024 + i]; }
    out[OUT_HBG + i] = m - d;
  }
  if (i == 0) {
    float s = 0.f;
    for (int k = 0; k < 256; ++k) s += recon_p[k];
    out[OUT_RECON] = s * (1.0f / 16777216.0f);  // /(B*V)
  }
}

extern "C" void kernel_launch(void* const* d_in, const int* in_sizes, int n_in,
                              void* d_out, int out_size, void* d_ws, size_t ws_size,
                              hipStream_t stream) {
  (void)in_sizes; (void)n_in; (void)out_size;
  const float* v   = (const float*)d_in[0];
  const float* w   = (const float*)d_in[1];
  const float* vb  = (const float*)d_in[2];
  const float* hb  = (const float*)d_in[3];
  const float* u_h = (const float*)d_in[4];
  const float* u_v = (const float*)d_in[5];
  float* out = (float*)d_out;
  char* ws = (char*)d_ws;
  if (ws_size < 204734464ULL) return;

  float* sums    = (float*)ws;               // 3.25 MiB region
  float* recon_p = sums;                     // 256
  float* vbd_p   = sums + 1024;              // 128*2048
  float* hbd_p   = vbd_p + 128 * 2048;       // 128*1024
  float* vbm_p   = hbd_p + 128 * 1024;       // 64*2048
  float* hbm_p   = vbm_p + 128 * 2048;       // 128*1024
  char* p = ws + 3407872;
  u16* v_cat  = (u16*)p;  p += (size_t)Bn * 2 * Vn * 2;   // 64 MiB [B,2V]
  u16* wT_cat = (u16*)p;  p += (size_t)Hn * 2 * Vn * 2;   // 8 MiB [H,2V]
  u16* w_cat  = (u16*)p;  p += (size_t)Vn * 2 * Hn * 2;   // 8 MiB [V,2H]
  u16* h_p    = (u16*)p;  p += BH * 2;                    // 16 MiB [B,H]
  u16* hbin   = (u16*)p;  p += BH * 2;                    // 16 MiB [B,H]
  u16* vT     = (u16*)p;  p += (size_t)Vn * Bn * 2;       // 32 MiB [V,B]
  u16* hT     = (u16*)p;  p += (size_t)Hn * Bn * 2;       // 16 MiB [H,B]
  float* big  = (float*)p;                                // 32 MiB time-shared
  u16* vk   = v_cat;            // v_cat dead after G2 (G3 partials overwrite)
  u16* vkT  = vT;               // vT dead after G3
  u16* h2T  = hT;               // hT dead after G3
  float* vcat_f = (float*)v_cat;   // 64 MiB: G3's 8 partials
  float* hpbuf  = (float*)h_p;     // h_p+hbin region (32 MiB) as f32 partials
  float* outW   = out + OUT_WGRAD;

  prep_all_k<<<4608, 256, 0, stream>>>(v, v_cat, vT, vbd_p, w, w_cat, wT_cat);
  // G1a: split-K x2 partials (z0 -> out[0..BH) scratch, z1 -> big)
  gemm256<1><<<dim3(32, 4, 2), 512, 0, stream>>>(
      v_cat, 2 * Vn, wT_cat, 2 * Vn, 3072, nullptr, nullptr, nullptr,
      out, nullptr, nullptr, big, nullptr, nullptr);
  // epi: h_pred / h_p / hbin / hT / hbd
  epi_h_k<1><<<dim3(128, 16), 256, 0, stream>>>(
      out, big, hb, u_h, out, h_p, hbin, hT, hbd_p);
  // G2: recon partials (256 blocks); aux16 = v_cat hi (still live)
  gemm256<2><<<dim3(32, 8), 512, 0, stream>>>(
      h_p, Hn, w_cat, 2 * Hn, Hn, vb, nullptr, nullptr,
      nullptr, nullptr, v_cat, recon_p, nullptr, nullptr);
  // G3: w_data_grad partials (split-K x8 -> v_cat region, 64 MiB)
  gemm256<3><<<dim3(Vn / 256, Hn / 256, 8), 512, 0, stream>>>(
      vT, Bn, hT, Bn, 1024, nullptr, nullptr, nullptr,
      vcat_f, nullptr, nullptr, vcat_f + 4 * VH, nullptr, nullptr);
  reduce8_k<<<2048, 256, 0, stream>>>(vcat_f, outW);   // outW = data-grad sum
  // G4: vk/vkT + vbm partials (fused sample+transpose epilogue)
  gemm256<4><<<dim3(32, 8), 512, 0, stream>>>(
      hbin, Hn, w_cat, 2 * Hn, 2 * Hn, vb, u_v, nullptr,
      nullptr, vk, nullptr, nullptr, vkT, vbm_p);
  // G5a: split-K x2 partials (z0 -> hpbuf, z1 -> big); h_p/hbin dead now
  gemm256<5><<<dim3(32, 4, 2), 512, 0, stream>>>(
      vk, Vn, wT_cat, 2 * Vn, 2048, nullptr, nullptr, nullptr,
      hpbuf, nullptr, nullptr, big, nullptr, nullptr);
  // epi: h2T + hbm
  epi_h_k<5><<<dim3(128, 16), 256, 0, stream>>>(
      hpbuf, big, hb, u_h + BH, nullptr, nullptr, nullptr, h2T, hbm_p);
  // G6: w_model_grad partials (split-K x8: z<4 -> hpbuf, z>=4 -> big)
  gemm256<3><<<dim3(Vn / 256, Hn / 256, 8), 512, 0, stream>>>(
      vkT, Bn, h2T, Bn, 1024, nullptr, nullptr, nullptr,
      hpbuf, nullptr, nullptr, big, nullptr, nullptr);
  reduce8s_k<<<2048, 256, 0, stream>>>(hpbuf, big, outW, outW);  // model - data
  finalize_k<<<8, 256, 0, stream>>>(sums, out);
}

// Round 8
// 498.631 us; speedup vs baseline: 1.1128x; 1.0088x over previous
//
#include <hip/hip_runtime.h>

// RBM CD-1 step on MI355X — round 16.
// = round-15 kernel (verified 503.0us, best) + concurrency merges (no
// numerics change):
//  (1) G2+G3 -> one 512-block launch g23_k: flat<256 = G2 (recon epilogue),
//      flat>=256 = G3 (split-K grad partials, z-slice XCD swizzle preserved:
//      offset 256 == 0 mod 8). Unified main loop (K=1024, NT=32); G2's
//      epilogue-heavy tail overlaps G3's MFMA-heavy start; one less boundary.
//  (2) reduce8s+finalize -> tail_k (2056 blocks, disjoint out regions).
// gemm256 modes 1/4/5 and G6 (mode 3) byte-identical to r15.

typedef unsigned short u16;
typedef short s16x8 __attribute__((ext_vector_type(8)));
typedef float f32x4 __attribute__((ext_vector_type(4)));
typedef u16 u16x4 __attribute__((ext_vector_type(4)));
typedef u16 u16x8 __attribute__((ext_vector_type(8)));

constexpr int Bn = 8192, Vn = 2048, Hn = 1024;
constexpr size_t VH = (size_t)Vn * Hn;
constexpr size_t BH = (size_t)Bn * Hn;
constexpr size_t OUT_RECON = BH;                        // 8388608
constexpr size_t OUT_WGRAD = OUT_RECON + 1;             // 8388609
constexpr size_t OUT_VBG   = OUT_WGRAD + VH;            // 10485761
constexpr size_t OUT_HBG   = OUT_VBG + Vn;              // 10487809

__device__ __forceinline__ u16 f2bf(float x) {
  union { float f; unsigned u; } a; a.f = x;
  unsigned r = a.u + 0x7FFFu + ((a.u >> 16) & 1u);   // RNE
  return (u16)(r >> 16);
}
__device__ __forceinline__ float bf2f(u16 h) {
  union { unsigned u; float f; } a; a.u = ((unsigned)h) << 16;
  return a.f;
}
__device__ __forceinline__ float sigmoidf_(float x) {
  return 1.0f / (1.0f + __expf(-x));
}

using gptr_t = const unsigned int __attribute__((address_space(1)))*;
using lptr_t = unsigned int __attribute__((address_space(3)))*;

__device__ __forceinline__ void gload16(const u16* g, u16* l) {
  __builtin_amdgcn_global_load_lds((gptr_t)(unsigned long long)g,
                                   (lptr_t)(unsigned long long)l, 16, 0, 0);
}

// ---------------- merged prep kernel ----------------
// blocks [0,4096): v[B,V] f32 -> v_cat[B,2V]=[hi|lo], vT[V,B], vbd partials.
// blocks [4096,4608): w[V,H] f32 -> w_cat[V,2H], wT_cat[H,2V].
__global__ void prep_all_k(const float* __restrict__ v, u16* __restrict__ vcat,
                           u16* __restrict__ vT, float* __restrict__ vbd_p,
                           const float* __restrict__ w, u16* __restrict__ w_cat,
                           u16* __restrict__ wTc) {
  __shared__ u16 tile16[64][68];
  __shared__ float cs[16][64];
  __shared__ float tile32[64][65];
  const int bx = blockIdx.x;
  const int t = threadIdx.x;
  if (bx < 4096) {
    const int b0 = (bx & 127) << 6, c0 = (bx >> 7) << 6;
    const int rg = t >> 4;          // 0..15 row group
    const int cg = (t & 15) << 2;   // col *4
    float ca[4] = {0.f, 0.f, 0.f, 0.f};
#pragma unroll
    for (int i = 0; i < 4; ++i) {
      int r = rg + 16 * i;
      f32x4 x = *(const f32x4*)&v[(size_t)(b0 + r) * Vn + c0 + cg];
      u16x4 hi, lo;
#pragma unroll
      for (int j = 0; j < 4; ++j) {
        hi[j] = f2bf(x[j]);
        lo[j] = f2bf(x[j] - bf2f(hi[j]));
        tile16[r][cg + j] = hi[j];
        ca[j] += x[j];
      }
      *(u16x4*)&vcat[(size_t)(b0 + r) * (2 * Vn) + c0 + cg] = hi;
      *(u16x4*)&vcat[(size_t)(b0 + r) * (2 * Vn) + Vn + c0 + cg] = lo;
    }
#pragma unroll
    for (int j = 0; j < 4; ++j) cs[rg][cg + j] = ca[j];
    __syncthreads();
    if (t < 64) {
      float s = 0.f;
#pragma unroll
      for (int k = 0; k < 16; ++k) s += cs[k][t];
      vbd_p[(size_t)(bx & 127) * Vn + c0 + t] = s;   // [128][2048]
    }
#pragma unroll
    for (int s2 = 0; s2 < 2; ++s2) {
      int c = t >> 2;
      int seg = (t & 3) + 4 * s2;
      u16x8 pk;
#pragma unroll
      for (int i = 0; i < 8; ++i) pk[i] = tile16[seg * 8 + i][c];
      *(u16x8*)&vT[(size_t)(c0 + c) * Bn + b0 + seg * 8] = pk;
    }
  } else {
    const int wb = bx - 4096;
    const int v0 = (wb & 31) << 6, h0 = (wb >> 5) << 6;
    const int c = t & 63, r = t >> 6;
    for (int rr = r; rr < 64; rr += 4) {
      float x = w[(size_t)(v0 + rr) * Hn + h0 + c];
      tile32[rr][c] = x;
      u16 hi = f2bf(x), lo = f2bf(x - bf2f(hi));
      w_cat[(size_t)(v0 + rr) * (2 * Hn) + h0 + c]      = hi;
      w_cat[(size_t)(v0 + rr) * (2 * Hn) + Hn + h0 + c] = lo;
    }
    __syncthreads();
    for (int rr = r; rr < 64; rr += 4) {
      float x = tile32[c][rr];  // = w[v0+c][h0+rr]
      u16 hi = f2bf(x), lo = f2bf(x - bf2f(hi));
      size_t ro = (size_t)(h0 + rr) * (2 * Vn);
      wTc[ro + v0 + c]      = hi;
      wTc[ro + Vn + v0 + c] = lo;
    }
  }
}

// ---- sampling epilogue for split-K [B,H] pre-activations ----------------
template <int M>
__global__ void epi_h_k(const float* __restrict__ p0, const float* __restrict__ p1,
                        const float* __restrict__ bias, const float* __restrict__ uni,
                        float* __restrict__ f32out, u16* __restrict__ hp_out,
                        u16* __restrict__ hbin_out, u16* __restrict__ tout,
                        float* __restrict__ colp) {
  __shared__ u16 tile[64][68];
  __shared__ float cs[16][64];
  const int b0 = blockIdx.x * 64, c0 = blockIdx.y * 64;
  const int t = threadIdx.x;
  const int rg = t >> 4, cg = (t & 15) << 2;
  float ca[4] = {0.f, 0.f, 0.f, 0.f};
#pragma unroll
  for (int i = 0; i < 4; ++i) {
    int r = rg + 16 * i;
    size_t e = (size_t)(b0 + r) * Hn + c0 + cg;
    f32x4 a = *(const f32x4*)&p0[e];
    f32x4 b = *(const f32x4*)&p1[e];
    f32x4 uu = *(const f32x4*)&uni[e];
    f32x4 hpv;
    u16x4 hb16, qv;
#pragma unroll
    for (int j = 0; j < 4; ++j) {
      float hp = sigmoidf_(a[j] + b[j] + bias[c0 + cg + j]);
      u16 qb = (hp > uu[j]) ? (u16)0x3F80 : (u16)0;
      tile[r][cg + j] = qb;
      if constexpr (M == 1) {
        hpv[j] = hp; hb16[j] = f2bf(hp); qv[j] = qb;
        ca[j] += hp;
      } else {
        ca[j] += (qb ? 1.f : 0.f);
      }
    }
    if constexpr (M == 1) {
      *(f32x4*)&f32out[e] = hpv;        // h_prediction (overwrites p0 region)
      *(u16x4*)&hp_out[e] = hb16;
      *(u16x4*)&hbin_out[e] = qv;
    }
  }
#pragma unroll
  for (int j = 0; j < 4; ++j) cs[rg][cg + j] = ca[j];
  __syncthreads();
  if (t < 64) {
    float s = 0.f;
#pragma unroll
    for (int k = 0; k < 16; ++k) s += cs[k][t];
    colp[(size_t)blockIdx.x * Hn + c0 + t] = s;   // [128][1024]
  }
#pragma unroll
  for (int s2 = 0; s2 < 2; ++s2) {
    int c = t >> 2;
    int seg = (t & 3) + 4 * s2;
    u16x8 pk;
#pragma unroll
    for (int i = 0; i < 8; ++i) pk[i] = tile[seg * 8 + i][c];
    *(u16x8*)&tout[(size_t)(c0 + c) * Bn + b0 + seg * 8] = pk;
  }
}

// ---------------- GEMM 256x256, BK=32, 8 waves, depth-4 counted pipeline --
// MODE 1: G1 split-K x2 partial (A remap [hi|hi|lo], B remap [hi|lo|hi]).
// MODE 3: split-K x8 grad (G6): A,B += z*K cols -> (z<4?f32out:redp)+(z&3)*VH.
// MODE 4: G4 vk: A=hbin (dup), B=w_cat, K=2048 -> vk, vkT, vbm (fused).
// MODE 5: G5 split-K x2 partial: A=vk (dup), B=wT_cat.
template <int MODE>
__global__ __launch_bounds__(512) void gemm256(
    const u16* __restrict__ A, int lda, const u16* __restrict__ Bm, int ldb, int K,
    const float* __restrict__ bias, const float* __restrict__ uni,
    const float* __restrict__ aux, float* __restrict__ f32out,
    u16* __restrict__ bfout, const u16* __restrict__ aux16,
    float* __restrict__ redp, u16* __restrict__ tout, float* __restrict__ colp) {
  constexpr bool TRANS = (MODE == 4);
  // As[4][256][32] at 0 (32768 u16), Bs[4][256][32] at 32768; 128 KB.
  // MODE4 epilogue ebuf [256][264] (67584 u16 = 132 KB) aliases everything.
  __shared__ __align__(16) u16 smem[TRANS ? 67584 : 65536];
  const int t = threadIdx.x;
  const int lane = t & 63, wave = t >> 6;                // 8 waves
  const int wr = (wave >> 2) << 7;                       // 0 / 128
  const int wc = (wave & 3) << 6;                        // 0/64/128/192
  // MODE-3-only XCD swizzle: grid (8,4,8), z = K-slice. HW: XCD = linear%8
  // (confirmed r12). Remap so XCD k owns z-slice k's full 8x4 MxN grid.
  int bidx = blockIdx.x, bidy = blockIdx.y, bidz = blockIdx.z;
  if constexpr (MODE == 3) {
    const int orig = blockIdx.x + (blockIdx.y << 3) + (blockIdx.z << 5);
    bidz = orig & 7;
    const int r = orig >> 3;       // 0..31 rank within XCD
    bidx = r & 7;
    bidy = r >> 3;
  }
  const int bm = bidx << 8, bn = bidy << 8;
  int kbeg = 0;
  float* pout = f32out;
  if constexpr (MODE == 1 || MODE == 5) {
    kbeg = bidz * K;
    pout = (bidz == 0) ? f32out : redp;
  }
  if constexpr (MODE == 3) {
    size_t off = (size_t)bidz * (size_t)K;
    A += off;
    Bm += off;
    pout = ((bidz < 4) ? f32out : redp) + (size_t)(bidz & 3) * VH;
  }
  f32x4 acc[8][4] = {};
  // staging (one gload = 512 thr x 16B = 128 rows x 64B): LDS row sr = t>>2,
  // granule t&3; fetch SWIZZLED global granule (t&3) ^ ((row>>1)&3) [r5 T2].
  const int sr = t >> 2;
  const int sc = (((t & 3) ^ ((t >> 3) & 3)) << 3);
  const u16* Ag  = A  + (size_t)(bm + sr) * lda + sc;
  const u16* Ag2 = Ag + (size_t)128 * lda;
  const u16* Bg  = Bm + (size_t)(bn + sr) * ldb + sc;
  const u16* Bg2 = Bg + (size_t)128 * ldb;
  const int fr = lane & 15, fg = lane >> 4;
  const int ga = ((fg ^ ((fr >> 1) & 3)) << 3);          // swizzled read granule

  auto stage = [&](int kt) {
    const int k0 = kbeg + (kt << 5);
    int acol, bcol;
    if constexpr (MODE == 1) {
      acol = (k0 < 2048) ? k0 : k0 - 2048;               // [hi|hi|lo]
      bcol = (k0 < 4096) ? k0 : k0 - 4096;               // [hi|lo|hi]
    } else if constexpr (MODE == 4) { acol = k0 & 1023; bcol = k0; }
    else if constexpr (MODE == 5)   { acol = k0 & 2047; bcol = k0; }
    else                            { acol = k0;        bcol = k0; }
    const int pb = kt & 3;
    u16* ad = smem + pb * 8192 + wave * 512;             // wave-uniform base
    u16* bd = smem + 32768 + pb * 8192 + wave * 512;
    gload16(Ag + acol, ad);
    gload16(Ag2 + acol, ad + 4096);
    gload16(Bg + bcol, bd);
    gload16(Bg2 + bcol, bd + 4096);
  };
  auto compute = [&](int kt) {
    const int pb = kt & 3;
    const u16* Ab = smem + pb * 8192;
    const u16* Bb = smem + 32768 + pb * 8192;
    s16x8 bf[4], af[4];
#pragma unroll
    for (int n = 0; n < 4; ++n)
      bf[n] = *(const s16x8*)&Bb[(wc + n * 16 + fr) * 32 + ga];
#pragma unroll
    for (int m = 0; m < 4; ++m)
      af[m] = *(const s16x8*)&Ab[(wr + m * 16 + fr) * 32 + ga];
    __builtin_amdgcn_s_setprio(1);
#pragma unroll
    for (int m = 0; m < 4; ++m)
#pragma unroll
      for (int n = 0; n < 4; ++n)
        acc[m][n] = __builtin_amdgcn_mfma_f32_16x16x32_bf16(af[m], bf[n], acc[m][n], 0, 0, 0);
    __builtin_amdgcn_s_setprio(0);
#pragma unroll
    for (int m = 0; m < 4; ++m)
      af[m] = *(const s16x8*)&Ab[(wr + (m + 4) * 16 + fr) * 32 + ga];
    __builtin_amdgcn_s_setprio(1);
#pragma unroll
    for (int m = 0; m < 4; ++m)
#pragma unroll
      for (int n = 0; n < 4; ++n)
        acc[m + 4][n] = __builtin_amdgcn_mfma_f32_16x16x32_bf16(af[m], bf[n], acc[m + 4][n], 0, 0, 0);
    __builtin_amdgcn_s_setprio(0);
  };
  // MODE 4 epilogue-tile L2 prefetch: one probe per 128B L2 line;
  // uni f32 [256][256] tile = 2048 lines = 4 chunks x 512 thr.
  auto pfl4 = [&](int ci) -> float {
    const int L = (ci << 9) + t;         // 0..2047
    return uni[(size_t)(bm + (L >> 3)) * Vn + bn + ((L & 7) << 5)];
  };

  // depth-4 pipeline: stage T+3 each iter; vmcnt(8) waits own tile-T loads
  // (12 outstanding -> 8); barrier publishes all waves' slices.
  const int NT = K >> 5;               // >= 32 for all modes
  const int pfbeg = NT - 8;            // probes at T in [NT-8, ...)
  stage(0); stage(1); stage(2);
  int T = 0;
  for (; T < NT - 3; ++T) {
    asm volatile("s_waitcnt vmcnt(8)" ::: "memory");
    __builtin_amdgcn_s_barrier();
    asm volatile("" ::: "memory");
    stage(T + 3);
    if constexpr (MODE == 4) {
      if (T >= pfbeg && T < pfbeg + 4) {
        float pfv = pfl4(T - pfbeg);
        asm volatile("" :: "v"(pfv));
      }
    }
    compute(T);
  }
  asm volatile("s_waitcnt vmcnt(8)" ::: "memory");
  __builtin_amdgcn_s_barrier();
  asm volatile("" ::: "memory");
  compute(T++);
  asm volatile("s_waitcnt vmcnt(4)" ::: "memory");
  __builtin_amdgcn_s_barrier();
  asm volatile("" ::: "memory");
  compute(T++);
  asm volatile("s_waitcnt vmcnt(0)" ::: "memory");
  __builtin_amdgcn_s_barrier();
  asm volatile("" ::: "memory");
  compute(T);

  // ---- epilogue ----
  constexpr int NC = (MODE == 4) ? Vn : Hn;
  const int fq = lane >> 4;

  if constexpr (MODE == 1 || MODE == 3 || MODE == 5) {
#pragma unroll
    for (int m = 0; m < 8; ++m)
#pragma unroll
      for (int n = 0; n < 4; ++n)
#pragma unroll
        for (int j = 0; j < 4; ++j) {
          int rl = wr + m * 16 + fq * 4 + j;
          int cl = wc + n * 16 + fr;
          pout[(size_t)(bm + rl) * NC + bn + cl] = acc[m][n][j];
        }
  }

  if constexpr (MODE == 4) {
    __syncthreads();   // all waves done with dbuf before ebuf writes
    float bcol[4];
#pragma unroll
    for (int n = 0; n < 4; ++n) bcol[n] = bias[bn + wc + n * 16 + fr];
    const size_t ebase = (size_t)(bm + wr + fq * 4) * NC + (bn + wc + fr);
    float ux[8][4];
    auto ld4 = [&](int ci, float* dst) {
      size_t e0 = ebase + (size_t)((ci >> 2) << 4) * NC + ((ci & 3) << 4);
      dst[0] = uni[e0];          dst[1] = uni[e0 + NC];
      dst[2] = uni[e0 + 2 * NC]; dst[3] = uni[e0 + 3 * NC];
    };
#pragma unroll
    for (int ci = 0; ci < 8; ++ci) ld4(ci, ux[ci]);
#pragma unroll
    for (int m = 0; m < 8; ++m)
#pragma unroll
      for (int n = 0; n < 4; ++n)
#pragma unroll
        for (int j = 0; j < 4; ++j)
          acc[m][n][j] = sigmoidf_(acc[m][n][j] + bcol[n]);
    float csum[4] = {0.f, 0.f, 0.f, 0.f};
#pragma unroll
    for (int ci = 0; ci < 32; ++ci) {
      const int m = ci >> 2, n = ci & 3;
      const int rl = wr + m * 16 + fq * 4;
      const int cl = wc + n * 16 + fr;
#pragma unroll
      for (int j = 0; j < 4; ++j) {
        u16 qb = (acc[m][n][j] > ux[ci & 7][j]) ? (u16)0x3F80 : (u16)0;
        smem[(rl + j) * 264 + cl] = qb;          // ebuf (feeds vk AND vkT)
        csum[n] += (qb ? 1.f : 0.f);
      }
      if (ci < 24) ld4(ci + 8, ux[ci & 7]);
    }
    // vbm partials: lane covers 32 rows; xor16+xor32 reduces fq -> 128 rows
#pragma unroll
    for (int n = 0; n < 4; ++n) {
      float s = csum[n];
      s += __shfl_xor(s, 16);
      s += __shfl_xor(s, 32);
      if (fq == 0)
        colp[(size_t)(blockIdx.x * 2 + (wr >> 7)) * NC + (bn + wc + n * 16 + fr)] = s;
    }
    __syncthreads();   // ebuf fully written
    // vk row-major writeout: coalesced u16x8 from ebuf. 256 rows x 32
    // col-chunks = 8192 tasks / 512 thr; consecutive threads fill one row.
#pragma unroll
    for (int it = 0; it < 16; ++it) {
      int id = t + (it << 9);
      int r = id >> 5;                   // 0..255
      int c0 = (id & 31) << 3;           // 0..248
      u16x8 pk = *(const u16x8*)&smem[r * 264 + c0];
      *(u16x8*)&bfout[(size_t)(bm + r) * NC + bn + c0] = pk;
    }
    // transposed write-out, 64B-contiguous per thread: thread owns
    // (col c, 32-row span q*32); 4x u16x8 stores land in ONE 64B line.
#pragma unroll
    for (int it = 0; it < 4; ++it) {
      int id = t + (it << 9);
      int c = id & 255;
      int q = id >> 8;                   // 0..7
#pragma unroll
      for (int i8 = 0; i8 < 4; ++i8) {
        u16x8 pk;
#pragma unroll
        for (int i2 = 0; i2 < 8; ++i2)
          pk[i2] = smem[(q * 32 + i8 * 8 + i2) * 264 + c];
        *(u16x8*)&tout[(size_t)(bn + c) * Bn + bm + q * 32 + i8 * 8] = pk;
      }
    }
  }
}

// ---------------- merged G2+G3 (512 blocks, one launch) -------------------
// flat < 256:  G2 recon. A=h_p[B,H], B=w_cat hi, K=1024, NC=2048;
//              epilogue: sigmoid + |v_hi - vp| partial -> redp2[bidy*32+bidx].
// flat >= 256: G3 grad. A=vT+z*1024, B=hT+z*1024 (ld=Bn), K=1024, NC=1024;
//              z-slice XCD swizzle (flat%8 preserved: 256 == 0 mod 8).
__global__ __launch_bounds__(512) void g23_k(
    const u16* __restrict__ A2, const u16* __restrict__ B2,
    const u16* __restrict__ aux16, const float* __restrict__ bias2,
    float* __restrict__ redp2,
    const u16* __restrict__ A3, const u16* __restrict__ B3,
    float* __restrict__ out30, float* __restrict__ out34) {
  __shared__ __align__(16) u16 smem[65536];
  const int t = threadIdx.x;
  const int lane = t & 63, wave = t >> 6;
  const int wr = (wave >> 2) << 7;
  const int wc = (wave & 3) << 6;
  const int flat = blockIdx.x;
  const bool isG2 = (flat < 256);
  int bidx, bidy, bidz = 0;
  const u16 *Abase, *Bbase;
  int lda, ldb;
  if (isG2) {
    bidx = flat & 31; bidy = flat >> 5;
    Abase = A2; Bbase = B2; lda = Hn; ldb = 2 * Hn;
  } else {
    const int orig = flat - 256;
    bidz = orig & 7;
    const int rr = orig >> 3;          // 0..31 rank within XCD
    bidx = rr & 7; bidy = rr >> 3;
    Abase = A3 + (size_t)bidz * 1024;
    Bbase = B3 + (size_t)bidz * 1024;
    lda = Bn; ldb = Bn;
  }
  const int bm = bidx << 8, bn = bidy << 8;
  f32x4 acc[8][4] = {};
  const int sr = t >> 2;
  const int sc = (((t & 3) ^ ((t >> 3) & 3)) << 3);
  const u16* Ag  = Abase + (size_t)(bm + sr) * lda + sc;
  const u16* Ag2 = Ag + (size_t)128 * lda;
  const u16* Bg  = Bbase + (size_t)(bn + sr) * ldb + sc;
  const u16* Bg2 = Bg + (size_t)128 * ldb;
  const int fr = lane & 15, fg = lane >> 4;
  const int ga = ((fg ^ ((fr >> 1) & 3)) << 3);

  auto stage = [&](int kt) {
    const int k0 = kt << 5;
    const int pb = kt & 3;
    u16* ad = smem + pb * 8192 + wave * 512;
    u16* bd = smem + 32768 + pb * 8192 + wave * 512;
    gload16(Ag + k0, ad);
    gload16(Ag2 + k0, ad + 4096);
    gload16(Bg + k0, bd);
    gload16(Bg2 + k0, bd + 4096);
  };
  auto compute = [&](int kt) {
    const int pb = kt & 3;
    const u16* Ab = smem + pb * 8192;
    const u16* Bb = smem + 32768 + pb * 8192;
    s16x8 bf[4], af[4];
#pragma unroll
    for (int n = 0; n < 4; ++n)
      bf[n] = *(const s16x8*)&Bb[(wc + n * 16 + fr) * 32 + ga];
#pragma unroll
    for (int m = 0; m < 4; ++m)
      af[m] = *(const s16x8*)&Ab[(wr + m * 16 + fr) * 32 + ga];
    __builtin_amdgcn_s_setprio(1);
#pragma unroll
    for (int m = 0; m < 4; ++m)
#pragma unroll
      for (int n = 0; n < 4; ++n)
        acc[m][n] = __builtin_amdgcn_mfma_f32_16x16x32_bf16(af[m], bf[n], acc[m][n], 0, 0, 0);
    __builtin_amdgcn_s_setprio(0);
#pragma unroll
    for (int m = 0; m < 4; ++m)
      af[m] = *(const s16x8*)&Ab[(wr + (m + 4) * 16 + fr) * 32 + ga];
    __builtin_amdgcn_s_setprio(1);
#pragma unroll
    for (int m = 0; m < 4; ++m)
#pragma unroll
      for (int n = 0; n < 4; ++n)
        acc[m + 4][n] = __builtin_amdgcn_mfma_f32_16x16x32_bf16(af[m], bf[n], acc[m + 4][n], 0, 0, 0);
    __builtin_amdgcn_s_setprio(0);
  };
  auto pfl2 = [&](int ci) -> unsigned {
    const int L = (ci << 9) + t;         // 0..1023
    return (unsigned)aux16[(size_t)(bm + (L >> 2)) * 4096 + bn + ((L & 3) << 6)];
  };

  constexpr int NT = 32;
  stage(0); stage(1); stage(2);
  int T = 0;
  for (; T < NT - 3; ++T) {
    asm volatile("s_waitcnt vmcnt(8)" ::: "memory");
    __builtin_amdgcn_s_barrier();
    asm volatile("" ::: "memory");
    stage(T + 3);
    if (isG2 && T >= NT - 8 && T < NT - 6) {
      unsigned pfv = pfl2(T - (NT - 8));
      asm volatile("" :: "v"(pfv));
    }
    compute(T);
  }
  asm volatile("s_waitcnt vmcnt(8)" ::: "memory");
  __builtin_amdgcn_s_barrier();
  asm volatile("" ::: "memory");
  compute(T++);
  asm volatile("s_waitcnt vmcnt(4)" ::: "memory");
  __builtin_amdgcn_s_barrier();
  asm volatile("" ::: "memory");
  compute(T++);
  asm volatile("s_waitcnt vmcnt(0)" ::: "memory");
  __builtin_amdgcn_s_barrier();
  asm volatile("" ::: "memory");
  compute(T);

  const int fq = lane >> 4;
  if (isG2) {
    // pipelined recon vs v_cat-hi (u16, stride 4096), depth-8 window (&7).
    float bcol[4];
#pragma unroll
    for (int n = 0; n < 4; ++n) bcol[n] = bias2[bn + wc + n * 16 + fr];
    const size_t ebase = (size_t)(bm + wr + fq * 4) * 4096 + (bn + wc + fr);
    float ax[8][4];
    auto ld4 = [&](int ci, float* dst) {
      size_t e0 = ebase + (size_t)((ci >> 2) << 4) * 4096 + ((ci & 3) << 4);
      dst[0] = bf2f(aux16[e0]);            dst[1] = bf2f(aux16[e0 + 4096]);
      dst[2] = bf2f(aux16[e0 + 2 * 4096]); dst[3] = bf2f(aux16[e0 + 3 * 4096]);
    };
#pragma unroll
    for (int ci = 0; ci < 8; ++ci) ld4(ci, ax[ci]);
#pragma unroll
    for (int m = 0; m < 8; ++m)
#pragma unroll
      for (int n = 0; n < 4; ++n)
#pragma unroll
        for (int j = 0; j < 4; ++j)
          acc[m][n][j] = sigmoidf_(acc[m][n][j] + bcol[n]);
    float lsum = 0.f;
#pragma unroll
    for (int ci = 0; ci < 32; ++ci) {
      const int m = ci >> 2, n = ci & 3;
#pragma unroll
      for (int j = 0; j < 4; ++j) lsum += fabsf(ax[ci & 7][j] - acc[m][n][j]);
      if (ci < 24) ld4(ci + 8, ax[ci & 7]);
    }
#pragma unroll
    for (int off = 32; off > 0; off >>= 1) lsum += __shfl_down(lsum, off);
    __syncthreads();
    float* redlds = (float*)smem;
    if (lane == 0) redlds[wave] = lsum;
    __syncthreads();
    if (t == 0) {
      float s = 0.f;
#pragma unroll
      for (int wv = 0; wv < 8; ++wv) s += redlds[wv];
      redp2[(size_t)bidy * 32 + bidx] = s;
    }
  } else {
    float* pout = ((bidz < 4) ? out30 : out34) + (size_t)(bidz & 3) * VH;
#pragma unroll
    for (int m = 0; m < 8; ++m)
#pragma unroll
      for (int n = 0; n < 4; ++n)
#pragma unroll
        for (int j = 0; j < 4; ++j) {
          int rl = wr + m * 16 + fq * 4 + j;
          int cl = wc + n * 16 + fr;
          pout[(size_t)(bm + rl) * Hn + bn + cl] = acc[m][n][j];
        }
  }
}

// out[i] = sum_{z<8} p[z][i]  (scalar stores: out base misaligned)
__global__ void reduce8_k(const float* __restrict__ p, float* __restrict__ out) {
  size_t e = ((size_t)blockIdx.x * 256 + threadIdx.x) * 4;
  f32x4 r = {};
#pragma unroll
  for (int z = 0; z < 8; ++z) r += *(const f32x4*)&p[(size_t)z * VH + e];
  out[e + 0] = r[0]; out[e + 1] = r[1]; out[e + 2] = r[2]; out[e + 3] = r[3];
}

// merged tail: blocks <2048 = reduce8s (w_grad = model partials - data grad),
// blocks >=2048 (8) = finalize (bias grads + recon scalar).
__global__ void tail_k(const float* __restrict__ pa, const float* __restrict__ pb,
                       const float* __restrict__ sums, float* __restrict__ out) {
  const int b = blockIdx.x;
  float* outw = out + OUT_WGRAD;
  if (b < 2048) {
    size_t e = ((size_t)b * 256 + threadIdx.x) * 4;
    f32x4 r = {};
#pragma unroll
    for (int z = 0; z < 4; ++z) r += *(const f32x4*)&pa[(size_t)z * VH + e];
#pragma unroll
    for (int z = 0; z < 4; ++z) r += *(const f32x4*)&pb[(size_t)z * VH + e];
    float s0 = outw[e + 0], s1 = outw[e + 1], s2 = outw[e + 2], s3 = outw[e + 3];
    outw[e + 0] = r[0] - s0; outw[e + 1] = r[1] - s1;
    outw[e + 2] = r[2] - s2; outw[e + 3] = r[3] - s3;
  } else {
    const int i = (b - 2048) * 256 + threadIdx.x;   // 0..2047
    const float* recon_p = sums;                 // 256
    const float* vbd = sums + 1024;              // 128 x 2048
    const float* hbd = vbd + 128 * 2048;         // 128 x 1024
    const float* vbm = hbd + 128 * 1024;         // 64 x 2048
    const float* hbm = vbm + 128 * 2048;         // 128 x 1024
    if (i < 2048) {
      float d = 0.f, m = 0.f;
      for (int k = 0; k < 128; ++k) d += vbd[k * 2048 + i];
      for (int k = 0; k < 64; ++k)  m += vbm[k * 2048 + i];
      out[OUT_VBG + i] = m - d;
    }
    if (i < 1024) {
      float d = 0.f, m = 0.f;
      for (int k = 0; k < 128; ++k) { d += hbd[k * 1024 + i]; m += hbm[k * 1024 + i]; }
      out[OUT_HBG + i] = m - d;
    }
    if (i == 0) {
      float s = 0.f;
      for (int k = 0; k < 256; ++k) s += recon_p[k];
      out[OUT_RECON] = s * (1.0f / 16777216.0f);  // /(B*V)
    }
  }
}

extern "C" void kernel_launch(void* const* d_in, const int* in_sizes, int n_in,
                              void* d_out, int out_size, void* d_ws, size_t ws_size,
                              hipStream_t stream) {
  (void)in_sizes; (void)n_in; (void)out_size;
  const float* v   = (const float*)d_in[0];
  const float* w   = (const float*)d_in[1];
  const float* vb  = (const float*)d_in[2];
  const float* hb  = (const float*)d_in[3];
  const float* u_h = (const float*)d_in[4];
  const float* u_v = (const float*)d_in[5];
  float* out = (float*)d_out;
  char* ws = (char*)d_ws;
  if (ws_size < 204734464ULL) return;

  float* sums    = (float*)ws;               // 3.25 MiB region
  float* recon_p = sums;                     // 256
  float* vbd_p   = sums + 1024;              // 128*2048
  float* hbd_p   = vbd_p + 128 * 2048;       // 128*1024
  float* vbm_p   = hbd_p + 128 * 1024;       // 64*2048
  float* hbm_p   = vbm_p + 128 * 2048;       // 128*1024
  char* p = ws + 3407872;
  u16* v_cat  = (u16*)p;  p += (size_t)Bn * 2 * Vn * 2;   // 64 MiB [B,2V]
  u16* wT_cat = (u16*)p;  p += (size_t)Hn * 2 * Vn * 2;   // 8 MiB [H,2V]
  u16* w_cat  = (u16*)p;  p += (size_t)Vn * 2 * Hn * 2;   // 8 MiB [V,2H]
  u16* h_p    = (u16*)p;  p += BH * 2;                    // 16 MiB [B,H]
  u16* hbin   = (u16*)p;  p += BH * 2;                    // 16 MiB [B,H]
  u16* vT     = (u16*)p;  p += (size_t)Vn * Bn * 2;       // 32 MiB [V,B]
  u16* hT     = (u16*)p;  p += (size_t)Hn * Bn * 2;       // 16 MiB [H,B]
  float* big  = (float*)p;                                // 32 MiB time-shared
  u16* vk   = v_cat;            // v_cat dead after g23 (G3 partials overwrite)
  u16* vkT  = vT;               // vT dead after g23
  u16* h2T  = hT;               // hT dead after g23
  float* vcat_f = (float*)v_cat;   // 64 MiB: G3's 8 partials
  float* hpbuf  = (float*)h_p;     // h_p+hbin region (32 MiB) as f32 partials
  float* outW   = out + OUT_WGRAD;

  prep_all_k<<<4608, 256, 0, stream>>>(v, v_cat, vT, vbd_p, w, w_cat, wT_cat);
  // G1a: split-K x2 partials (z0 -> out[0..BH) scratch, z1 -> big)
  gemm256<1><<<dim3(32, 4, 2), 512, 0, stream>>>(
      v_cat, 2 * Vn, wT_cat, 2 * Vn, 3072, nullptr, nullptr, nullptr,
      out, nullptr, nullptr, big, nullptr, nullptr);
  // epi: h_pred / h_p / hbin / hT / hbd
  epi_h_k<1><<<dim3(128, 16), 256, 0, stream>>>(
      out, big, hb, u_h, out, h_p, hbin, hT, hbd_p);
  // merged G2 (recon) + G3 (w_data_grad partials): 512 blocks, one launch
  g23_k<<<512, 512, 0, stream>>>(
      h_p, w_cat, v_cat, vb, recon_p,
      vT, hT, vcat_f, vcat_f + 4 * VH);
  reduce8_k<<<2048, 256, 0, stream>>>(vcat_f, outW);   // outW = data-grad sum
  // G4: vk/vkT + vbm partials (fused sample+transpose epilogue)
  gemm256<4><<<dim3(32, 8), 512, 0, stream>>>(
      hbin, Hn, w_cat, 2 * Hn, 2 * Hn, vb, u_v, nullptr,
      nullptr, vk, nullptr, nullptr, vkT, vbm_p);
  // G5a: split-K x2 partials (z0 -> hpbuf, z1 -> big); h_p/hbin dead now
  gemm256<5><<<dim3(32, 4, 2), 512, 0, stream>>>(
      vk, Vn, wT_cat, 2 * Vn, 2048, nullptr, nullptr, nullptr,
      hpbuf, nullptr, nullptr, big, nullptr, nullptr);
  // epi: h2T + hbm
  epi_h_k<5><<<dim3(128, 16), 256, 0, stream>>>(
      hpbuf, big, hb, u_h + BH, nullptr, nullptr, nullptr, h2T, hbm_p);
  // G6: w_model_grad partials (split-K x8: z<4 -> hpbuf, z>=4 -> big)
  gemm256<3><<<dim3(Vn / 256, Hn / 256, 8), 512, 0, stream>>>(
      vkT, Bn, h2T, Bn, 1024, nullptr, nullptr, nullptr,
      hpbuf, nullptr, nullptr, big, nullptr, nullptr);
  // merged reduce8s + finalize
  tail_k<<<2056, 256, 0, stream>>>(hpbuf, big, sums, out);
}

// Round 9
// 492.250 us; speedup vs baseline: 1.1272x; 1.0130x over previous
//
#include <hip/hip_runtime.h>

// RBM CD-1 step on MI355X — round 17.
// = round-16 kernel (verified 498.6us, best) + 2-phase-per-K-tile schedule
// port [T3+T4 regime] in gemm256 AND g23_k main loops. Pure schedule edit:
// identical LDS layout/addressing/vmcnt counts; each 32-K-tile becomes
//   phase A: {ds bf0-3+af0-3; stage A-half of kt+3; barrier; 16 MFMA lo}
//   phase B: {ds af4-7; stage B-half of kt+3; vmcnt(8|4|0); barrier; 16 MFMA hi}
// ds_reads issue BEFORE each barrier (latency absorbed by barrier wait);
// stage gloads spread 2/phase; counted vmcnt guards tile kt+1 exactly as the
// r16 loop did (12 outstanding -> 8). Everything else byte-identical to r16.

typedef unsigned short u16;
typedef short s16x8 __attribute__((ext_vector_type(8)));
typedef float f32x4 __attribute__((ext_vector_type(4)));
typedef u16 u16x4 __attribute__((ext_vector_type(4)));
typedef u16 u16x8 __attribute__((ext_vector_type(8)));

constexpr int Bn = 8192, Vn = 2048, Hn = 1024;
constexpr size_t VH = (size_t)Vn * Hn;
constexpr size_t BH = (size_t)Bn * Hn;
constexpr size_t OUT_RECON = BH;                        // 8388608
constexpr size_t OUT_WGRAD = OUT_RECON + 1;             // 8388609
constexpr size_t OUT_VBG   = OUT_WGRAD + VH;            // 10485761
constexpr size_t OUT_HBG   = OUT_VBG + Vn;              // 10487809

__device__ __forceinline__ u16 f2bf(float x) {
  union { float f; unsigned u; } a; a.f = x;
  unsigned r = a.u + 0x7FFFu + ((a.u >> 16) & 1u);   // RNE
  return (u16)(r >> 16);
}
__device__ __forceinline__ float bf2f(u16 h) {
  union { unsigned u; float f; } a; a.u = ((unsigned)h) << 16;
  return a.f;
}
__device__ __forceinline__ float sigmoidf_(float x) {
  return 1.0f / (1.0f + __expf(-x));
}

using gptr_t = const unsigned int __attribute__((address_space(1)))*;
using lptr_t = unsigned int __attribute__((address_space(3)))*;

__device__ __forceinline__ void gload16(const u16* g, u16* l) {
  __builtin_amdgcn_global_load_lds((gptr_t)(unsigned long long)g,
                                   (lptr_t)(unsigned long long)l, 16, 0, 0);
}

// ---------------- merged prep kernel ----------------
// blocks [0,4096): v[B,V] f32 -> v_cat[B,2V]=[hi|lo], vT[V,B], vbd partials.
// blocks [4096,4608): w[V,H] f32 -> w_cat[V,2H], wT_cat[H,2V].
__global__ void prep_all_k(const float* __restrict__ v, u16* __restrict__ vcat,
                           u16* __restrict__ vT, float* __restrict__ vbd_p,
                           const float* __restrict__ w, u16* __restrict__ w_cat,
                           u16* __restrict__ wTc) {
  __shared__ u16 tile16[64][68];
  __shared__ float cs[16][64];
  __shared__ float tile32[64][65];
  const int bx = blockIdx.x;
  const int t = threadIdx.x;
  if (bx < 4096) {
    const int b0 = (bx & 127) << 6, c0 = (bx >> 7) << 6;
    const int rg = t >> 4;          // 0..15 row group
    const int cg = (t & 15) << 2;   // col *4
    float ca[4] = {0.f, 0.f, 0.f, 0.f};
#pragma unroll
    for (int i = 0; i < 4; ++i) {
      int r = rg + 16 * i;
      f32x4 x = *(const f32x4*)&v[(size_t)(b0 + r) * Vn + c0 + cg];
      u16x4 hi, lo;
#pragma unroll
      for (int j = 0; j < 4; ++j) {
        hi[j] = f2bf(x[j]);
        lo[j] = f2bf(x[j] - bf2f(hi[j]));
        tile16[r][cg + j] = hi[j];
        ca[j] += x[j];
      }
      *(u16x4*)&vcat[(size_t)(b0 + r) * (2 * Vn) + c0 + cg] = hi;
      *(u16x4*)&vcat[(size_t)(b0 + r) * (2 * Vn) + Vn + c0 + cg] = lo;
    }
#pragma unroll
    for (int j = 0; j < 4; ++j) cs[rg][cg + j] = ca[j];
    __syncthreads();
    if (t < 64) {
      float s = 0.f;
#pragma unroll
      for (int k = 0; k < 16; ++k) s += cs[k][t];
      vbd_p[(size_t)(bx & 127) * Vn + c0 + t] = s;   // [128][2048]
    }
#pragma unroll
    for (int s2 = 0; s2 < 2; ++s2) {
      int c = t >> 2;
      int seg = (t & 3) + 4 * s2;
      u16x8 pk;
#pragma unroll
      for (int i = 0; i < 8; ++i) pk[i] = tile16[seg * 8 + i][c];
      *(u16x8*)&vT[(size_t)(c0 + c) * Bn + b0 + seg * 8] = pk;
    }
  } else {
    const int wb = bx - 4096;
    const int v0 = (wb & 31) << 6, h0 = (wb >> 5) << 6;
    const int c = t & 63, r = t >> 6;
    for (int rr = r; rr < 64; rr += 4) {
      float x = w[(size_t)(v0 + rr) * Hn + h0 + c];
      tile32[rr][c] = x;
      u16 hi = f2bf(x), lo = f2bf(x - bf2f(hi));
      w_cat[(size_t)(v0 + rr) * (2 * Hn) + h0 + c]      = hi;
      w_cat[(size_t)(v0 + rr) * (2 * Hn) + Hn + h0 + c] = lo;
    }
    __syncthreads();
    for (int rr = r; rr < 64; rr += 4) {
      float x = tile32[c][rr];  // = w[v0+c][h0+rr]
      u16 hi = f2bf(x), lo = f2bf(x - bf2f(hi));
      size_t ro = (size_t)(h0 + rr) * (2 * Vn);
      wTc[ro + v0 + c]      = hi;
      wTc[ro + Vn + v0 + c] = lo;
    }
  }
}

// ---- sampling epilogue for split-K [B,H] pre-activations ----------------
template <int M>
__global__ void epi_h_k(const float* __restrict__ p0, const float* __restrict__ p1,
                        const float* __restrict__ bias, const float* __restrict__ uni,
                        float* __restrict__ f32out, u16* __restrict__ hp_out,
                        u16* __restrict__ hbin_out, u16* __restrict__ tout,
                        float* __restrict__ colp) {
  __shared__ u16 tile[64][68];
  __shared__ float cs[16][64];
  const int b0 = blockIdx.x * 64, c0 = blockIdx.y * 64;
  const int t = threadIdx.x;
  const int rg = t >> 4, cg = (t & 15) << 2;
  float ca[4] = {0.f, 0.f, 0.f, 0.f};
#pragma unroll
  for (int i = 0; i < 4; ++i) {
    int r = rg + 16 * i;
    size_t e = (size_t)(b0 + r) * Hn + c0 + cg;
    f32x4 a = *(const f32x4*)&p0[e];
    f32x4 b = *(const f32x4*)&p1[e];
    f32x4 uu = *(const f32x4*)&uni[e];
    f32x4 hpv;
    u16x4 hb16, qv;
#pragma unroll
    for (int j = 0; j < 4; ++j) {
      float hp = sigmoidf_(a[j] + b[j] + bias[c0 + cg + j]);
      u16 qb = (hp > uu[j]) ? (u16)0x3F80 : (u16)0;
      tile[r][cg + j] = qb;
      if constexpr (M == 1) {
        hpv[j] = hp; hb16[j] = f2bf(hp); qv[j] = qb;
        ca[j] += hp;
      } else {
        ca[j] += (qb ? 1.f : 0.f);
      }
    }
    if constexpr (M == 1) {
      *(f32x4*)&f32out[e] = hpv;        // h_prediction (overwrites p0 region)
      *(u16x4*)&hp_out[e] = hb16;
      *(u16x4*)&hbin_out[e] = qv;
    }
  }
#pragma unroll
  for (int j = 0; j < 4; ++j) cs[rg][cg + j] = ca[j];
  __syncthreads();
  if (t < 64) {
    float s = 0.f;
#pragma unroll
    for (int k = 0; k < 16; ++k) s += cs[k][t];
    colp[(size_t)blockIdx.x * Hn + c0 + t] = s;   // [128][1024]
  }
#pragma unroll
  for (int s2 = 0; s2 < 2; ++s2) {
    int c = t >> 2;
    int seg = (t & 3) + 4 * s2;
    u16x8 pk;
#pragma unroll
    for (int i = 0; i < 8; ++i) pk[i] = tile[seg * 8 + i][c];
    *(u16x8*)&tout[(size_t)(c0 + c) * Bn + b0 + seg * 8] = pk;
  }
}

// ---------------- GEMM 256x256, BK=32, 8 waves, 2-phase counted pipeline --
// MODE 1: G1 split-K x2 partial (A remap [hi|hi|lo], B remap [hi|lo|hi]).
// MODE 3: split-K x8 grad (G6): A,B += z*K cols -> (z<4?f32out:redp)+(z&3)*VH.
// MODE 4: G4 vk: A=hbin (dup), B=w_cat, K=2048 -> vk, vkT, vbm (fused).
// MODE 5: G5 split-K x2 partial: A=vk (dup), B=wT_cat.
template <int MODE>
__global__ __launch_bounds__(512) void gemm256(
    const u16* __restrict__ A, int lda, const u16* __restrict__ Bm, int ldb, int K,
    const float* __restrict__ bias, const float* __restrict__ uni,
    const float* __restrict__ aux, float* __restrict__ f32out,
    u16* __restrict__ bfout, const u16* __restrict__ aux16,
    float* __restrict__ redp, u16* __restrict__ tout, float* __restrict__ colp) {
  constexpr bool TRANS = (MODE == 4);
  // As[4][256][32] at 0 (32768 u16), Bs[4][256][32] at 32768; 128 KB.
  // MODE4 epilogue ebuf [256][264] (67584 u16 = 132 KB) aliases everything.
  __shared__ __align__(16) u16 smem[TRANS ? 67584 : 65536];
  const int t = threadIdx.x;
  const int lane = t & 63, wave = t >> 6;                // 8 waves
  const int wr = (wave >> 2) << 7;                       // 0 / 128
  const int wc = (wave & 3) << 6;                        // 0/64/128/192
  // MODE-3-only XCD swizzle: grid (8,4,8), z = K-slice. HW: XCD = linear%8
  // (confirmed r12). Remap so XCD k owns z-slice k's full 8x4 MxN grid.
  int bidx = blockIdx.x, bidy = blockIdx.y, bidz = blockIdx.z;
  if constexpr (MODE == 3) {
    const int orig = blockIdx.x + (blockIdx.y << 3) + (blockIdx.z << 5);
    bidz = orig & 7;
    const int r = orig >> 3;       // 0..31 rank within XCD
    bidx = r & 7;
    bidy = r >> 3;
  }
  const int bm = bidx << 8, bn = bidy << 8;
  int kbeg = 0;
  float* pout = f32out;
  if constexpr (MODE == 1 || MODE == 5) {
    kbeg = bidz * K;
    pout = (bidz == 0) ? f32out : redp;
  }
  if constexpr (MODE == 3) {
    size_t off = (size_t)bidz * (size_t)K;
    A += off;
    Bm += off;
    pout = ((bidz < 4) ? f32out : redp) + (size_t)(bidz & 3) * VH;
  }
  f32x4 acc[8][4] = {};
  // staging (one gload = 512 thr x 16B = 128 rows x 64B): LDS row sr = t>>2,
  // granule t&3; fetch SWIZZLED global granule (t&3) ^ ((row>>1)&3) [r5 T2].
  const int sr = t >> 2;
  const int sc = (((t & 3) ^ ((t >> 3) & 3)) << 3);
  const u16* Ag  = A  + (size_t)(bm + sr) * lda + sc;
  const u16* Ag2 = Ag + (size_t)128 * lda;
  const u16* Bg  = Bm + (size_t)(bn + sr) * ldb + sc;
  const u16* Bg2 = Bg + (size_t)128 * ldb;
  const int fr = lane & 15, fg = lane >> 4;
  const int ga = ((fg ^ ((fr >> 1) & 3)) << 3);          // swizzled read granule

  auto acolf = [&](int k0) -> int {
    if constexpr (MODE == 1)      return (k0 < 2048) ? k0 : k0 - 2048;  // [hi|hi|lo]
    else if constexpr (MODE == 4) return k0 & 1023;
    else if constexpr (MODE == 5) return k0 & 2047;
    else                          return k0;
  };
  auto bcolf = [&](int k0) -> int {
    if constexpr (MODE == 1) return (k0 < 4096) ? k0 : k0 - 4096;       // [hi|lo|hi]
    else                     return k0;
  };
  auto stageA = [&](int kt) {
    const int k0 = kbeg + (kt << 5);
    const int acol = acolf(k0);
    u16* ad = smem + (kt & 3) * 8192 + wave * 512;       // wave-uniform base
    gload16(Ag + acol, ad);
    gload16(Ag2 + acol, ad + 4096);
  };
  auto stageB = [&](int kt) {
    const int k0 = kbeg + (kt << 5);
    const int bcol = bcolf(k0);
    u16* bd = smem + 32768 + (kt & 3) * 8192 + wave * 512;
    gload16(Bg + bcol, bd);
    gload16(Bg2 + bcol, bd + 4096);
  };
  // MODE 4 epilogue-tile L2 prefetch: one probe per 128B L2 line;
  // uni f32 [256][256] tile = 2048 lines = 4 chunks x 512 thr.
  auto pfl4 = [&](int ci) -> float {
    const int L = (ci << 9) + t;         // 0..2047
    return uni[(size_t)(bm + (L >> 3)) * Vn + bn + ((L & 7) << 5)];
  };

  // 2-phase-per-tile counted pipeline (depth-4 slabs, pb = kt&3):
  // steady outstanding at phase-B vmcnt = 12 -> vmcnt(8) guards tile kt+1.
  const int NT = K >> 5;               // >= 32 for all modes
  const int pfbeg = NT - 8;            // probes at kt in [NT-8, NT-4)
  stageA(0); stageB(0); stageA(1); stageB(1); stageA(2); stageB(2);
  asm volatile("s_waitcnt vmcnt(8)" ::: "memory");
  __builtin_amdgcn_s_barrier();
  asm volatile("" ::: "memory");
  s16x8 bf[4], af[4];
  for (int kt = 0; kt < NT; ++kt) {
    const int pb = kt & 3;
    const u16* Ab = smem + pb * 8192;
    const u16* Bb = smem + 32768 + pb * 8192;
    const bool st = (kt < NT - 3);
    // ---- phase A: reads + A-stage + barrier + MFMA lo ----
#pragma unroll
    for (int n = 0; n < 4; ++n)
      bf[n] = *(const s16x8*)&Bb[(wc + n * 16 + fr) * 32 + ga];
#pragma unroll
    for (int m = 0; m < 4; ++m)
      af[m] = *(const s16x8*)&Ab[(wr + m * 16 + fr) * 32 + ga];
    if (st) stageA(kt + 3);
    if constexpr (MODE == 4) {
      if (kt >= pfbeg && kt < pfbeg + 4) {
        float pfv = pfl4(kt - pfbeg);
        asm volatile("" :: "v"(pfv));
      }
    }
    __builtin_amdgcn_s_barrier();
    asm volatile("" ::: "memory");
    __builtin_amdgcn_s_setprio(1);
#pragma unroll
    for (int m = 0; m < 4; ++m)
#pragma unroll
      for (int n = 0; n < 4; ++n)
        acc[m][n] = __builtin_amdgcn_mfma_f32_16x16x32_bf16(af[m], bf[n], acc[m][n], 0, 0, 0);
    __builtin_amdgcn_s_setprio(0);
    // ---- phase B: reads + B-stage + vmcnt + barrier + MFMA hi ----
#pragma unroll
    for (int m = 0; m < 4; ++m)
      af[m] = *(const s16x8*)&Ab[(wr + (m + 4) * 16 + fr) * 32 + ga];
    if (st) stageB(kt + 3);
    if (kt < NT - 3) {
      asm volatile("s_waitcnt vmcnt(8)" ::: "memory");
    } else if (kt == NT - 3) {
      asm volatile("s_waitcnt vmcnt(4)" ::: "memory");
    } else if (kt == NT - 2) {
      asm volatile("s_waitcnt vmcnt(0)" ::: "memory");
    }
    __builtin_amdgcn_s_barrier();
    asm volatile("" ::: "memory");
    __builtin_amdgcn_s_setprio(1);
#pragma unroll
    for (int m = 0; m < 4; ++m)
#pragma unroll
      for (int n = 0; n < 4; ++n)
        acc[m + 4][n] = __builtin_amdgcn_mfma_f32_16x16x32_bf16(af[m], bf[n], acc[m + 4][n], 0, 0, 0);
    __builtin_amdgcn_s_setprio(0);
  }

  // ---- epilogue ----
  constexpr int NC = (MODE == 4) ? Vn : Hn;
  const int fq = lane >> 4;

  if constexpr (MODE == 1 || MODE == 3 || MODE == 5) {
#pragma unroll
    for (int m = 0; m < 8; ++m)
#pragma unroll
      for (int n = 0; n < 4; ++n)
#pragma unroll
        for (int j = 0; j < 4; ++j) {
          int rl = wr + m * 16 + fq * 4 + j;
          int cl = wc + n * 16 + fr;
          pout[(size_t)(bm + rl) * NC + bn + cl] = acc[m][n][j];
        }
  }

  if constexpr (MODE == 4) {
    __syncthreads();   // all waves done with dbuf before ebuf writes
    float bcol[4];
#pragma unroll
    for (int n = 0; n < 4; ++n) bcol[n] = bias[bn + wc + n * 16 + fr];
    const size_t ebase = (size_t)(bm + wr + fq * 4) * NC + (bn + wc + fr);
    float ux[8][4];
    auto ld4 = [&](int ci, float* dst) {
      size_t e0 = ebase + (size_t)((ci >> 2) << 4) * NC + ((ci & 3) << 4);
      dst[0] = uni[e0];          dst[1] = uni[e0 + NC];
      dst[2] = uni[e0 + 2 * NC]; dst[3] = uni[e0 + 3 * NC];
    };
#pragma unroll
    for (int ci = 0; ci < 8; ++ci) ld4(ci, ux[ci]);
#pragma unroll
    for (int m = 0; m < 8; ++m)
#pragma unroll
      for (int n = 0; n < 4; ++n)
#pragma unroll
        for (int j = 0; j < 4; ++j)
          acc[m][n][j] = sigmoidf_(acc[m][n][j] + bcol[n]);
    float csum[4] = {0.f, 0.f, 0.f, 0.f};
#pragma unroll
    for (int ci = 0; ci < 32; ++ci) {
      const int m = ci >> 2, n = ci & 3;
      const int rl = wr + m * 16 + fq * 4;
      const int cl = wc + n * 16 + fr;
#pragma unroll
      for (int j = 0; j < 4; ++j) {
        u16 qb = (acc[m][n][j] > ux[ci & 7][j]) ? (u16)0x3F80 : (u16)0;
        smem[(rl + j) * 264 + cl] = qb;          // ebuf (feeds vk AND vkT)
        csum[n] += (qb ? 1.f : 0.f);
      }
      if (ci < 24) ld4(ci + 8, ux[ci & 7]);
    }
    // vbm partials: lane covers 32 rows; xor16+xor32 reduces fq -> 128 rows
#pragma unroll
    for (int n = 0; n < 4; ++n) {
      float s = csum[n];
      s += __shfl_xor(s, 16);
      s += __shfl_xor(s, 32);
      if (fq == 0)
        colp[(size_t)(blockIdx.x * 2 + (wr >> 7)) * NC + (bn + wc + n * 16 + fr)] = s;
    }
    __syncthreads();   // ebuf fully written
    // vk row-major writeout: coalesced u16x8 from ebuf. 256 rows x 32
    // col-chunks = 8192 tasks / 512 thr; consecutive threads fill one row.
#pragma unroll
    for (int it = 0; it < 16; ++it) {
      int id = t + (it << 9);
      int r = id >> 5;                   // 0..255
      int c0 = (id & 31) << 3;           // 0..248
      u16x8 pk = *(const u16x8*)&smem[r * 264 + c0];
      *(u16x8*)&bfout[(size_t)(bm + r) * NC + bn + c0] = pk;
    }
    // transposed write-out, 64B-contiguous per thread: thread owns
    // (col c, 32-row span q*32); 4x u16x8 stores land in ONE 64B line.
#pragma unroll
    for (int it = 0; it < 4; ++it) {
      int id = t + (it << 9);
      int c = id & 255;
      int q = id >> 8;                   // 0..7
#pragma unroll
      for (int i8 = 0; i8 < 4; ++i8) {
        u16x8 pk;
#pragma unroll
        for (int i2 = 0; i2 < 8; ++i2)
          pk[i2] = smem[(q * 32 + i8 * 8 + i2) * 264 + c];
        *(u16x8*)&tout[(size_t)(bn + c) * Bn + bm + q * 32 + i8 * 8] = pk;
      }
    }
  }
}

// ---------------- merged G2+G3 (512 blocks, one launch) -------------------
// flat < 256:  G2 recon. A=h_p[B,H], B=w_cat hi, K=1024, NC=2048;
//              epilogue: sigmoid + |v_hi - vp| partial -> redp2[bidy*32+bidx].
// flat >= 256: G3 grad. A=vT+z*1024, B=hT+z*1024 (ld=Bn), K=1024, NC=1024;
//              z-slice XCD swizzle (flat%8 preserved: 256 == 0 mod 8).
__global__ __launch_bounds__(512) void g23_k(
    const u16* __restrict__ A2, const u16* __restrict__ B2,
    const u16* __restrict__ aux16, const float* __restrict__ bias2,
    float* __restrict__ redp2,
    const u16* __restrict__ A3, const u16* __restrict__ B3,
    float* __restrict__ out30, float* __restrict__ out34) {
  __shared__ __align__(16) u16 smem[65536];
  const int t = threadIdx.x;
  const int lane = t & 63, wave = t >> 6;
  const int wr = (wave >> 2) << 7;
  const int wc = (wave & 3) << 6;
  const int flat = blockIdx.x;
  const bool isG2 = (flat < 256);
  int bidx, bidy, bidz = 0;
  const u16 *Abase, *Bbase;
  int lda, ldb;
  if (isG2) {
    bidx = flat & 31; bidy = flat >> 5;
    Abase = A2; Bbase = B2; lda = Hn; ldb = 2 * Hn;
  } else {
    const int orig = flat - 256;
    bidz = orig & 7;
    const int rr = orig >> 3;          // 0..31 rank within XCD
    bidx = rr & 7; bidy = rr >> 3;
    Abase = A3 + (size_t)bidz * 1024;
    Bbase = B3 + (size_t)bidz * 1024;
    lda = Bn; ldb = Bn;
  }
  const int bm = bidx << 8, bn = bidy << 8;
  f32x4 acc[8][4] = {};
  const int sr = t >> 2;
  const int sc = (((t & 3) ^ ((t >> 3) & 3)) << 3);
  const u16* Ag  = Abase + (size_t)(bm + sr) * lda + sc;
  const u16* Ag2 = Ag + (size_t)128 * lda;
  const u16* Bg  = Bbase + (size_t)(bn + sr) * ldb + sc;
  const u16* Bg2 = Bg + (size_t)128 * ldb;
  const int fr = lane & 15, fg = lane >> 4;
  const int ga = ((fg ^ ((fr >> 1) & 3)) << 3);

  auto stageA = [&](int kt) {
    u16* ad = smem + (kt & 3) * 8192 + wave * 512;
    gload16(Ag + (kt << 5), ad);
    gload16(Ag2 + (kt << 5), ad + 4096);
  };
  auto stageB = [&](int kt) {
    u16* bd = smem + 32768 + (kt & 3) * 8192 + wave * 512;
    gload16(Bg + (kt << 5), bd);
    gload16(Bg2 + (kt << 5), bd + 4096);
  };
  auto pfl2 = [&](int ci) -> unsigned {
    const int L = (ci << 9) + t;         // 0..1023
    return (unsigned)aux16[(size_t)(bm + (L >> 2)) * 4096 + bn + ((L & 3) << 6)];
  };

  constexpr int NT = 32;
  stageA(0); stageB(0); stageA(1); stageB(1); stageA(2); stageB(2);
  asm volatile("s_waitcnt vmcnt(8)" ::: "memory");
  __builtin_amdgcn_s_barrier();
  asm volatile("" ::: "memory");
  s16x8 bf[4], af[4];
  for (int kt = 0; kt < NT; ++kt) {
    const int pb = kt & 3;
    const u16* Ab = smem + pb * 8192;
    const u16* Bb = smem + 32768 + pb * 8192;
    const bool st = (kt < NT - 3);
    // phase A
#pragma unroll
    for (int n = 0; n < 4; ++n)
      bf[n] = *(const s16x8*)&Bb[(wc + n * 16 + fr) * 32 + ga];
#pragma unroll
    for (int m = 0; m < 4; ++m)
      af[m] = *(const s16x8*)&Ab[(wr + m * 16 + fr) * 32 + ga];
    if (st) stageA(kt + 3);
    if (isG2 && kt >= NT - 8 && kt < NT - 6) {
      unsigned pfv = pfl2(kt - (NT - 8));
      asm volatile("" :: "v"(pfv));
    }
    __builtin_amdgcn_s_barrier();
    asm volatile("" ::: "memory");
    __builtin_amdgcn_s_setprio(1);
#pragma unroll
    for (int m = 0; m < 4; ++m)
#pragma unroll
      for (int n = 0; n < 4; ++n)
        acc[m][n] = __builtin_amdgcn_mfma_f32_16x16x32_bf16(af[m], bf[n], acc[m][n], 0, 0, 0);
    __builtin_amdgcn_s_setprio(0);
    // phase B
#pragma unroll
    for (int m = 0; m < 4; ++m)
      af[m] = *(const s16x8*)&Ab[(wr + (m + 4) * 16 + fr) * 32 + ga];
    if (st) stageB(kt + 3);
    if (kt < NT - 3) {
      asm volatile("s_waitcnt vmcnt(8)" ::: "memory");
    } else if (kt == NT - 3) {
      asm volatile("s_waitcnt vmcnt(4)" ::: "memory");
    } else if (kt == NT - 2) {
      asm volatile("s_waitcnt vmcnt(0)" ::: "memory");
    }
    __builtin_amdgcn_s_barrier();
    asm volatile("" ::: "memory");
    __builtin_amdgcn_s_setprio(1);
#pragma unroll
    for (int m = 0; m < 4; ++m)
#pragma unroll
      for (int n = 0; n < 4; ++n)
        acc[m + 4][n] = __builtin_amdgcn_mfma_f32_16x16x32_bf16(af[m], bf[n], acc[m + 4][n], 0, 0, 0);
    __builtin_amdgcn_s_setprio(0);
  }

  const int fq = lane >> 4;
  if (isG2) {
    // pipelined recon vs v_cat-hi (u16, stride 4096), depth-8 window (&7).
    float bcol[4];
#pragma unroll
    for (int n = 0; n < 4; ++n) bcol[n] = bias2[bn + wc + n * 16 + fr];
    const size_t ebase = (size_t)(bm + wr + fq * 4) * 4096 + (bn + wc + fr);
    float ax[8][4];
    auto ld4 = [&](int ci, float* dst) {
      size_t e0 = ebase + (size_t)((ci >> 2) << 4) * 4096 + ((ci & 3) << 4);
      dst[0] = bf2f(aux16[e0]);            dst[1] = bf2f(aux16[e0 + 4096]);
      dst[2] = bf2f(aux16[e0 + 2 * 4096]); dst[3] = bf2f(aux16[e0 + 3 * 4096]);
    };
#pragma unroll
    for (int ci = 0; ci < 8; ++ci) ld4(ci, ax[ci]);
#pragma unroll
    for (int m = 0; m < 8; ++m)
#pragma unroll
      for (int n = 0; n < 4; ++n)
#pragma unroll
        for (int j = 0; j < 4; ++j)
          acc[m][n][j] = sigmoidf_(acc[m][n][j] + bcol[n]);
    float lsum = 0.f;
#pragma unroll
    for (int ci = 0; ci < 32; ++ci) {
      const int m = ci >> 2, n = ci & 3;
#pragma unroll
      for (int j = 0; j < 4; ++j) lsum += fabsf(ax[ci & 7][j] - acc[m][n][j]);
      if (ci < 24) ld4(ci + 8, ax[ci & 7]);
    }
#pragma unroll
    for (int off = 32; off > 0; off >>= 1) lsum += __shfl_down(lsum, off);
    __syncthreads();
    float* redlds = (float*)smem;
    if (lane == 0) redlds[wave] = lsum;
    __syncthreads();
    if (t == 0) {
      float s = 0.f;
#pragma unroll
      for (int wv = 0; wv < 8; ++wv) s += redlds[wv];
      redp2[(size_t)bidy * 32 + bidx] = s;
    }
  } else {
    float* pout = ((bidz < 4) ? out30 : out34) + (size_t)(bidz & 3) * VH;
#pragma unroll
    for (int m = 0; m < 8; ++m)
#pragma unroll
      for (int n = 0; n < 4; ++n)
#pragma unroll
        for (int j = 0; j < 4; ++j) {
          int rl = wr + m * 16 + fq * 4 + j;
          int cl = wc + n * 16 + fr;
          pout[(size_t)(bm + rl) * Hn + bn + cl] = acc[m][n][j];
        }
  }
}

// out[i] = sum_{z<8} p[z][i]  (scalar stores: out base misaligned)
__global__ void reduce8_k(const float* __restrict__ p, float* __restrict__ out) {
  size_t e = ((size_t)blockIdx.x * 256 + threadIdx.x) * 4;
  f32x4 r = {};
#pragma unroll
  for (int z = 0; z < 8; ++z) r += *(const f32x4*)&p[(size_t)z * VH + e];
  out[e + 0] = r[0]; out[e + 1] = r[1]; out[e + 2] = r[2]; out[e + 3] = r[3];
}

// merged tail: blocks <2048 = reduce8s (w_grad = model partials - data grad),
// blocks >=2048 (8) = finalize (bias grads + recon scalar).
__global__ void tail_k(const float* __restrict__ pa, const float* __restrict__ pb,
                       const float* __restrict__ sums, float* __restrict__ out) {
  const int b = blockIdx.x;
  float* outw = out + OUT_WGRAD;
  if (b < 2048) {
    size_t e = ((size_t)b * 256 + threadIdx.x) * 4;
    f32x4 r = {};
#pragma unroll
    for (int z = 0; z < 4; ++z) r += *(const f32x4*)&pa[(size_t)z * VH + e];
#pragma unroll
    for (int z = 0; z < 4; ++z) r += *(const f32x4*)&pb[(size_t)z * VH + e];
    float s0 = outw[e + 0], s1 = outw[e + 1], s2 = outw[e + 2], s3 = outw[e + 3];
    outw[e + 0] = r[0] - s0; outw[e + 1] = r[1] - s1;
    outw[e + 2] = r[2] - s2; outw[e + 3] = r[3] - s3;
  } else {
    const int i = (b - 2048) * 256 + threadIdx.x;   // 0..2047
    const float* recon_p = sums;                 // 256
    const float* vbd = sums + 1024;              // 128 x 2048
    const float* hbd = vbd + 128 * 2048;         // 128 x 1024
    const float* vbm = hbd + 128 * 1024;         // 64 x 2048
    const float* hbm = vbm + 128 * 2048;         // 128 x 1024
    if (i < 2048) {
      float d = 0.f, m = 0.f;
      for (int k = 0; k < 128; ++k) d += vbd[k * 2048 + i];
      for (int k = 0; k < 64; ++k)  m += vbm[k * 2048 + i];
      out[OUT_VBG + i] = m - d;
    }
    if (i < 1024) {
      float d = 0.f, m = 0.f;
      for (int k = 0; k < 128; ++k) { d += hbd[k * 1024 + i]; m += hbm[k * 1024 + i]; }
      out[OUT_HBG + i] = m - d;
    }
    if (i == 0) {
      float s = 0.f;
      for (int k = 0; k < 256; ++k) s += recon_p[k];
      out[OUT_RECON] = s * (1.0f / 16777216.0f);  // /(B*V)
    }
  }
}

extern "C" void kernel_launch(void* const* d_in, const int* in_sizes, int n_in,
                              void* d_out, int out_size, void* d_ws, size_t ws_size,
                              hipStream_t stream) {
  (void)in_sizes; (void)n_in; (void)out_size;
  const float* v   = (const float*)d_in[0];
  const float* w   = (const float*)d_in[1];
  const float* vb  = (const float*)d_in[2];
  const float* hb  = (const float*)d_in[3];
  const float* u_h = (const float*)d_in[4];
  const float* u_v = (const float*)d_in[5];
  float* out = (float*)d_out;
  char* ws = (char*)d_ws;
  if (ws_size < 204734464ULL) return;

  float* sums    = (float*)ws;               // 3.25 MiB region
  float* recon_p = sums;                     // 256
  float* vbd_p   = sums + 1024;              // 128*2048
  float* hbd_p   = vbd_p + 128 * 2048;       // 128*1024
  float* vbm_p   = hbd_p + 128 * 1024;       // 64*2048
  float* hbm_p   = vbm_p + 128 * 2048;       // 128*1024
  char* p = ws + 3407872;
  u16* v_cat  = (u16*)p;  p += (size_t)Bn * 2 * Vn * 2;   // 64 MiB [B,2V]
  u16* wT_cat = (u16*)p;  p += (size_t)Hn * 2 * Vn * 2;   // 8 MiB [H,2V]
  u16* w_cat  = (u16*)p;  p += (size_t)Vn * 2 * Hn * 2;   // 8 MiB [V,2H]
  u16* h_p    = (u16*)p;  p += BH * 2;                    // 16 MiB [B,H]
  u16* hbin   = (u16*)p;  p += BH * 2;                    // 16 MiB [B,H]
  u16* vT     = (u16*)p;  p += (size_t)Vn * Bn * 2;       // 32 MiB [V,B]
  u16* hT     = (u16*)p;  p += (size_t)Hn * Bn * 2;       // 16 MiB [H,B]
  float* big  = (float*)p;                                // 32 MiB time-shared
  u16* vk   = v_cat;            // v_cat dead after g23 (G3 partials overwrite)
  u16* vkT  = vT;               // vT dead after g23
  u16* h2T  = hT;               // hT dead after g23
  float* vcat_f = (float*)v_cat;   // 64 MiB: G3's 8 partials
  float* hpbuf  = (float*)h_p;     // h_p+hbin region (32 MiB) as f32 partials
  float* outW   = out + OUT_WGRAD;

  prep_all_k<<<4608, 256, 0, stream>>>(v, v_cat, vT, vbd_p, w, w_cat, wT_cat);
  // G1a: split-K x2 partials (z0 -> out[0..BH) scratch, z1 -> big)
  gemm256<1><<<dim3(32, 4, 2), 512, 0, stream>>>(
      v_cat, 2 * Vn, wT_cat, 2 * Vn, 3072, nullptr, nullptr, nullptr,
      out, nullptr, nullptr, big, nullptr, nullptr);
  // epi: h_pred / h_p / hbin / hT / hbd
  epi_h_k<1><<<dim3(128, 16), 256, 0, stream>>>(
      out, big, hb, u_h, out, h_p, hbin, hT, hbd_p);
  // merged G2 (recon) + G3 (w_data_grad partials): 512 blocks, one launch
  g23_k<<<512, 512, 0, stream>>>(
      h_p, w_cat, v_cat, vb, recon_p,
      vT, hT, vcat_f, vcat_f + 4 * VH);
  reduce8_k<<<2048, 256, 0, stream>>>(vcat_f, outW);   // outW = data-grad sum
  // G4: vk/vkT + vbm partials (fused sample+transpose epilogue)
  gemm256<4><<<dim3(32, 8), 512, 0, stream>>>(
      hbin, Hn, w_cat, 2 * Hn, 2 * Hn, vb, u_v, nullptr,
      nullptr, vk, nullptr, nullptr, vkT, vbm_p);
  // G5a: split-K x2 partials (z0 -> hpbuf, z1 -> big); h_p/hbin dead now
  gemm256<5><<<dim3(32, 4, 2), 512, 0, stream>>>(
      vk, Vn, wT_cat, 2 * Vn, 2048, nullptr, nullptr, nullptr,
      hpbuf, nullptr, nullptr, big, nullptr, nullptr);
  // epi: h2T + hbm
  epi_h_k<5><<<dim3(128, 16), 256, 0, stream>>>(
      hpbuf, big, hb, u_h + BH, nullptr, nullptr, nullptr, h2T, hbm_p);
  // G6: w_model_grad partials (split-K x8: z<4 -> hpbuf, z>=4 -> big)
  gemm256<3><<<dim3(Vn / 256, Hn / 256, 8), 512, 0, stream>>>(
      vkT, Bn, h2T, Bn, 1024, nullptr, nullptr, nullptr,
      hpbuf, nullptr, nullptr, big, nullptr, nullptr);
  // merged reduce8s + finalize
  tail_k<<<2056, 256, 0, stream>>>(hpbuf, big, sums, out);
}